// Round 1
// baseline (1727.542 us; speedup 1.0000x reference)
//
#include <hip/hip_runtime.h>
#include <cstdint>
#include <cstddef>

typedef __attribute__((ext_vector_type(4))) float f32x4;
typedef __attribute__((ext_vector_type(8))) short short8;

// ---------- bf16 helpers (bit-level, header-version independent) ----------
__device__ __forceinline__ unsigned short f2bf(float f) {
  unsigned int u = __float_as_uint(f);
  u += 0x7fffu + ((u >> 16) & 1u);            // round to nearest even
  return (unsigned short)(u >> 16);
}
__device__ __forceinline__ float bf2f(unsigned short h) {
  return __uint_as_float(((unsigned int)h) << 16);
}

__device__ __forceinline__ void gload16(const unsigned short* g, unsigned short* l) {
  __builtin_amdgcn_global_load_lds(
      (const __attribute__((address_space(1))) void*)g,
      (__attribute__((address_space(3))) void*)l, 16, 0, 0);
}

// ---------- P1: split x f32 -> bf16 hi + lo ----------
__global__ __launch_bounds__(256) void k_split(const float* __restrict__ src,
                                               unsigned short* __restrict__ hi,
                                               unsigned short* __restrict__ lo) {
  size_t i = ((size_t)blockIdx.x * 256 + threadIdx.x) * 4;
  float4 v = *(const float4*)(src + i);
  unsigned short h0 = f2bf(v.x), h1 = f2bf(v.y), h2 = f2bf(v.z), h3 = f2bf(v.w);
  ushort4 hv = make_ushort4(h0, h1, h2, h3);
  ushort4 lv = make_ushort4(f2bf(v.x - bf2f(h0)), f2bf(v.y - bf2f(h1)),
                            f2bf(v.z - bf2f(h2)), f2bf(v.w - bf2f(h3)));
  *(ushort4*)(hi + i) = hv;
  *(ushort4*)(lo + i) = lv;
}

// ---------- P2/P3: transpose f32 [R][C] -> bf16 [C][R] (optionally split) ----------
template<bool SPLIT>
__global__ __launch_bounds__(256) void k_transpose(const float* __restrict__ src,
                                                   unsigned short* __restrict__ hi,
                                                   unsigned short* __restrict__ lo,
                                                   int R, int C) {
  __shared__ float tile[32][33];
  int tx = threadIdx.x & 31, ty = threadIdx.x >> 5;  // ty 0..7
  int c0 = blockIdx.x * 32, r0 = blockIdx.y * 32;
#pragma unroll
  for (int i = 0; i < 4; ++i)
    tile[ty + 8 * i][tx] = src[(size_t)(r0 + ty + 8 * i) * C + (c0 + tx)];
  __syncthreads();
#pragma unroll
  for (int i = 0; i < 4; ++i) {
    float v = tile[tx][ty + 8 * i];
    size_t o = (size_t)(c0 + ty + 8 * i) * R + (r0 + tx);
    unsigned short h = f2bf(v);
    hi[o] = h;
    if (SPLIT) lo[o] = f2bf(v - bf2f(h));
  }
}

// ---------- GEMM: A[M][K] (bf16, k-contig), B[N][K] (bf16, k-contig) -> C[M][N] f32
// 128x128 tile, BK=32, 4 waves, slot-major LDS [g][m][8] (conflict-free),
// SPLIT: acc += Ah*Bh + Ah*Bl + Al*Bh  (split-bf16 ~f32 precision)
template<bool SPLIT>
__global__ __launch_bounds__(256) void k_gemm(const unsigned short* __restrict__ Ah,
                                              const unsigned short* __restrict__ Al,
                                              const unsigned short* __restrict__ Bh,
                                              const unsigned short* __restrict__ Bl,
                                              float* __restrict__ C, int M, int N, int K) {
  constexpr int NARR = SPLIT ? 4 : 2;
  __shared__ unsigned short lds[NARR * 4096];
  const int tid = threadIdx.x, wave = tid >> 6, lane = tid & 63;
  const size_t row0 = (size_t)blockIdx.x * 128;
  const size_t col0 = (size_t)blockIdx.y * 128;
  const int wr = wave >> 1, wc = wave & 1;
  const int r16 = lane & 15;
  const int aoff = (lane >> 4) * 1024 + (wr * 64 + r16) * 8;
  const int boff = (lane >> 4) * 1024 + (wc * 64 + r16) * 8;

  f32x4 acc[4][4];
#pragma unroll
  for (int i = 0; i < 4; ++i)
#pragma unroll
    for (int j = 0; j < 4; ++j) acc[i][j] = (f32x4){0.f, 0.f, 0.f, 0.f};

  for (int k0 = 0; k0 < K; k0 += 32) {
#pragma unroll
    for (int i = 0; i < NARR * 2; ++i) {
      int L = wave * (NARR * 2) + i;
      int arr = L >> 3, gg = (L >> 1) & 3, mh = L & 1;
      const unsigned short* src;
      size_t grow;
      if (SPLIT) {
        src = (arr == 0) ? Ah : (arr == 1) ? Al : (arr == 2) ? Bh : Bl;
        grow = (arr < 2) ? row0 : col0;
      } else {
        src = (arr == 0) ? Ah : Bh;
        grow = (arr == 0) ? row0 : col0;
      }
      gload16(src + (grow + (size_t)(mh * 64 + lane)) * (size_t)K + (size_t)(k0 + 8 * gg),
              &lds[arr * 4096 + gg * 1024 + mh * 512]);
    }
    __syncthreads();
    short8 ah[4], bh[4], al[4], bl[4];
#pragma unroll
    for (int mb = 0; mb < 4; ++mb) {
      ah[mb] = *(const short8*)&lds[0 * 4096 + aoff + mb * 128];
      if (SPLIT) al[mb] = *(const short8*)&lds[1 * 4096 + aoff + mb * 128];
    }
#pragma unroll
    for (int nb = 0; nb < 4; ++nb) {
      bh[nb] = *(const short8*)&lds[(SPLIT ? 2 : 1) * 4096 + boff + nb * 128];
      if (SPLIT) bl[nb] = *(const short8*)&lds[3 * 4096 + boff + nb * 128];
    }
#pragma unroll
    for (int mb = 0; mb < 4; ++mb)
#pragma unroll
      for (int nb = 0; nb < 4; ++nb) {
        acc[mb][nb] = __builtin_amdgcn_mfma_f32_16x16x32_bf16(ah[mb], bh[nb], acc[mb][nb], 0, 0, 0);
        if (SPLIT) {
          acc[mb][nb] = __builtin_amdgcn_mfma_f32_16x16x32_bf16(ah[mb], bl[nb], acc[mb][nb], 0, 0, 0);
          acc[mb][nb] = __builtin_amdgcn_mfma_f32_16x16x32_bf16(al[mb], bh[nb], acc[mb][nb], 0, 0, 0);
        }
      }
    __syncthreads();
  }
  // C/D layout (HW-verified): col = lane&15, row = (lane>>4)*4 + reg
#pragma unroll
  for (int mb = 0; mb < 4; ++mb)
#pragma unroll
    for (int nb = 0; nb < 4; ++nb) {
      size_t row = row0 + wr * 64 + mb * 16 + (lane >> 4) * 4;
      size_t col = col0 + wc * 64 + nb * 16 + r16;
      float* cp = C + row * (size_t)N + col;
#pragma unroll
      for (int r = 0; r < 4; ++r) cp[(size_t)r * N] = acc[mb][nb][r];
    }
}

// ---------- scan constants ----------
#define SB 4
#define ST 4096
#define SE 2048
#define CHUNK 64
#define NCHUNK 64
#define NCHAIN (SB * SE)  // 8192

// K2: elementwise transforms + chunk-local scan (from -inf) + chunk summaries.
// Overwrites proj in place: slot e <- lv, slot E+e <- lc.
__global__ __launch_bounds__(256) void k_scan1(float* __restrict__ proj,
                                               const float* __restrict__ bfv,
                                               float* __restrict__ Ac,
                                               float* __restrict__ Bc) {
  int idx = blockIdx.x * 256 + threadIdx.x;  // (c, b, e) with e fastest
  int e = idx & (SE - 1), b = (idx >> 11) & 3, c = idx >> 13;
  const float bk = bfv[e], bh = bfv[SE + e];
  float A = 0.f, S = -INFINITY;
  size_t base = ((size_t)(b * ST + c * CHUNK) * (2 * SE)) + e;
  for (int i = 0; i < CHUNK; ++i) {
    float k = proj[base] + bk;
    float hx = proj[base + SE] + bh;
    float sp = fmaxf(k, 0.f) + log1pf(expf(-fabsf(k)));  // softplus(k)
    float lc = -sp;                                      // log(1-sigmoid(k))
    float lg = (hx >= 0.f) ? logf(hx + 0.5f) : (hx - log1pf(expf(hx)));
    float lv = lg + k + lc;                              // log_g + log_sigmoid(k)
    A += lc;
    float a1 = lc + S;
    float m = fmaxf(a1, lv);
    S = m + log1pf(expf(fminf(a1, lv) - m));
    proj[base] = lv;
    proj[base + SE] = lc;
    base += 2 * SE;
  }
  int chain = b * SE + e;
  Ac[(size_t)c * NCHAIN + chain] = A;
  Bc[(size_t)c * NCHAIN + chain] = S;
}

// K3: scan over chunk summaries -> incoming state per chunk
__global__ __launch_bounds__(256) void k_scan2(const float* __restrict__ lh0,
                                               const float* __restrict__ Ac,
                                               const float* __restrict__ Bc,
                                               float* __restrict__ Hin) {
  int chain = blockIdx.x * 256 + threadIdx.x;  // 8192 = b*E + e
  float H = lh0[chain];
  for (int c = 0; c < NCHUNK; ++c) {
    Hin[(size_t)c * NCHAIN + chain] = H;
    float a = Ac[(size_t)c * NCHAIN + chain] + H;
    float bv = Bc[(size_t)c * NCHAIN + chain];
    float m = fmaxf(a, bv);
    H = m + log1pf(expf(fminf(a, bv) - m));
  }
}

// K4: replay scan with true incoming state; emit h_t (bf16) and out2 slices (f32)
__global__ __launch_bounds__(256) void k_scan3(const float* __restrict__ proj,
                                               const float* __restrict__ Hin,
                                               unsigned short* __restrict__ ht,
                                               float* __restrict__ out2) {
  int idx = blockIdx.x * 256 + threadIdx.x;
  int e = idx & (SE - 1), b = (idx >> 11) & 3, c = idx >> 13;
  float S = Hin[(size_t)c * NCHAIN + b * SE + e];
  size_t base = ((size_t)(b * ST + c * CHUNK) * (2 * SE)) + e;
  int t = c * CHUNK;
  size_t hto = ((size_t)(b * ST + t) * SE) + e;
  for (int i = 0; i < CHUNK; ++i, ++t) {
    float lv = proj[base], lc = proj[base + SE];
    float a1 = lc + S;
    float m = fmaxf(a1, lv);
    S = m + log1pf(expf(fminf(a1, lv) - m));
    ht[hto] = f2bf(expf(S));
    if (t >= 2 && ((t - 2) % 3) == 0) {   // t in {2,5,...,4094}
      int j = (t - 2) / 3;
      out2[((size_t)b * 1365 + j) * SE + e] = S;
    }
    base += 2 * SE;
    hto += SE;
  }
}

// ---------- launch ----------
extern "C" void kernel_launch(void* const* d_in, const int* in_sizes, int n_in,
                              void* d_out, int out_size, void* d_ws, size_t ws_size,
                              hipStream_t stream) {
  const float* x   = (const float*)d_in[0];
  const float* lh0 = (const float*)d_in[1];
  const float* wf  = (const float*)d_in[2];
  const float* bfv = (const float*)d_in[3];
  const float* wd  = (const float*)d_in[4];
  float* out1 = (float*)d_out;
  float* out2 = out1 + (size_t)SB * ST * 1024;

  char* p = (char*)d_ws;
  float* proj          = (float*)p;          p += 16384ull * 4096 * 4;  // 268 MB
  unsigned short* xhi  = (unsigned short*)p; p += 16384ull * 1024 * 2;
  unsigned short* xlo  = (unsigned short*)p; p += 16384ull * 1024 * 2;
  unsigned short* wfh  = (unsigned short*)p; p += 4096ull * 1024 * 2;
  unsigned short* wfl  = (unsigned short*)p; p += 4096ull * 1024 * 2;
  unsigned short* wdt  = (unsigned short*)p; p += 1024ull * 2048 * 2;
  unsigned short* ht   = (unsigned short*)p; p += 16384ull * 2048 * 2;  // 67 MB
  float* Ac            = (float*)p;          p += 64ull * 8192 * 4;
  float* Bc            = (float*)p;          p += 64ull * 8192 * 4;
  float* Hin           = (float*)p;          p += 64ull * 8192 * 4;

  // pre-passes
  hipLaunchKernelGGL(k_split, dim3(16384), dim3(256), 0, stream, x, xhi, xlo);
  hipLaunchKernelGGL((k_transpose<true>),  dim3(128, 32), dim3(256), 0, stream, wf, wfh, wfl, 1024, 4096);
  hipLaunchKernelGGL((k_transpose<false>), dim3(32, 64),  dim3(256), 0, stream, wd, wdt, nullptr, 2048, 1024);
  // GEMM1 (split-bf16, ~f32 accuracy): proj = x @ w_f
  hipLaunchKernelGGL((k_gemm<true>), dim3(128, 32), dim3(256), 0, stream,
                     xhi, xlo, wfh, wfl, proj, 16384, 4096, 1024);
  // 3-pass chunked log-space scan
  hipLaunchKernelGGL(k_scan1, dim3(2048), dim3(256), 0, stream, proj, bfv, Ac, Bc);
  hipLaunchKernelGGL(k_scan2, dim3(32), dim3(256), 0, stream, lh0, Ac, Bc, Hin);
  hipLaunchKernelGGL(k_scan3, dim3(2048), dim3(256), 0, stream, proj, Hin, ht, out2);
  // GEMM2 (bf16): out1 = h_t @ w_down
  hipLaunchKernelGGL((k_gemm<false>), dim3(128, 8), dim3(256), 0, stream,
                     ht, nullptr, wdt, nullptr, out1, 16384, 1024, 2048);
}

// Round 2
// 1707.615 us; speedup vs baseline: 1.0117x; 1.0117x over previous
//
#include <hip/hip_runtime.h>
#include <cstdint>
#include <cstddef>

typedef __attribute__((ext_vector_type(4))) float f32x4;
typedef __attribute__((ext_vector_type(8))) short short8;

// ---------- bf16 helpers (bit-level, header-version independent) ----------
__device__ __forceinline__ unsigned short f2bf(float f) {
  unsigned int u = __float_as_uint(f);
  u += 0x7fffu + ((u >> 16) & 1u);            // round to nearest even
  return (unsigned short)(u >> 16);
}
__device__ __forceinline__ float bf2f(unsigned short h) {
  return __uint_as_float(((unsigned int)h) << 16);
}

__device__ __forceinline__ void gload16(const unsigned short* g, unsigned short* l) {
  __builtin_amdgcn_global_load_lds(
      (const __attribute__((address_space(1))) void*)g,
      (__attribute__((address_space(3))) void*)l, 16, 0, 0);
}

// ---------- P1: split x f32 -> bf16 hi + lo ----------
__global__ __launch_bounds__(256) void k_split(const float* __restrict__ src,
                                               unsigned short* __restrict__ hi,
                                               unsigned short* __restrict__ lo) {
  size_t i = ((size_t)blockIdx.x * 256 + threadIdx.x) * 4;
  float4 v = *(const float4*)(src + i);
  unsigned short h0 = f2bf(v.x), h1 = f2bf(v.y), h2 = f2bf(v.z), h3 = f2bf(v.w);
  ushort4 hv = make_ushort4(h0, h1, h2, h3);
  ushort4 lv = make_ushort4(f2bf(v.x - bf2f(h0)), f2bf(v.y - bf2f(h1)),
                            f2bf(v.z - bf2f(h2)), f2bf(v.w - bf2f(h3)));
  *(ushort4*)(hi + i) = hv;
  *(ushort4*)(lo + i) = lv;
}

// ---------- P2/P3: transpose f32 [R][C] -> bf16 [C][R] (optionally split) ----------
template<bool SPLIT>
__global__ __launch_bounds__(256) void k_transpose(const float* __restrict__ src,
                                                   unsigned short* __restrict__ hi,
                                                   unsigned short* __restrict__ lo,
                                                   int R, int C) {
  __shared__ float tile[32][33];
  int tx = threadIdx.x & 31, ty = threadIdx.x >> 5;  // ty 0..7
  int c0 = blockIdx.x * 32, r0 = blockIdx.y * 32;
#pragma unroll
  for (int i = 0; i < 4; ++i)
    tile[ty + 8 * i][tx] = src[(size_t)(r0 + ty + 8 * i) * C + (c0 + tx)];
  __syncthreads();
#pragma unroll
  for (int i = 0; i < 4; ++i) {
    float v = tile[tx][ty + 8 * i];
    size_t o = (size_t)(c0 + ty + 8 * i) * R + (r0 + tx);
    unsigned short h = f2bf(v);
    hi[o] = h;
    if (SPLIT) lo[o] = f2bf(v - bf2f(h));
  }
}

// ---------- GEMM: A[M][K] (bf16, k-contig), B[N][K] (bf16, k-contig) -> C[M][N] f32
// 128x128 tile, BK=32, 4 waves, slot-major LDS [g][m][8] (conflict-free, PMC-verified 0),
// 2-phase double-buffered prefetch: STAGE(next) issued BEFORE compute(cur),
// one __syncthreads (vmcnt(0)+lgkmcnt(0) drain) per K-step.
// SPLIT: acc += Ah*Bh + Ah*Bl + Al*Bh  (split-bf16 ~f32 precision)
template<bool SPLIT>
__global__ __launch_bounds__(256) void k_gemm(const unsigned short* __restrict__ Ah,
                                              const unsigned short* __restrict__ Al,
                                              const unsigned short* __restrict__ Bh,
                                              const unsigned short* __restrict__ Bl,
                                              float* __restrict__ C, int M, int N, int K) {
  constexpr int NARR = SPLIT ? 4 : 2;
  __shared__ unsigned short lds[2][NARR * 4096];
  const int tid = threadIdx.x, wave = tid >> 6, lane = tid & 63;
  const size_t row0 = (size_t)blockIdx.x * 128;
  const size_t col0 = (size_t)blockIdx.y * 128;
  const int wr = wave >> 1, wc = wave & 1;
  const int r16 = lane & 15;
  const int aoff = (lane >> 4) * 1024 + (wr * 64 + r16) * 8;
  const int boff = (lane >> 4) * 1024 + (wc * 64 + r16) * 8;

  f32x4 acc[4][4];
#pragma unroll
  for (int i = 0; i < 4; ++i)
#pragma unroll
    for (int j = 0; j < 4; ++j) acc[i][j] = (f32x4){0.f, 0.f, 0.f, 0.f};

  // stage one K-step (BK=32) of all NARR arrays into lds[buf]
  auto STAGE = [&](int buf, int k0) {
#pragma unroll
    for (int i = 0; i < NARR * 2; ++i) {
      int L = wave * (NARR * 2) + i;
      int arr = L >> 3, gg = (L >> 1) & 3, mh = L & 1;
      const unsigned short* src;
      size_t grow;
      if (SPLIT) {
        src = (arr == 0) ? Ah : (arr == 1) ? Al : (arr == 2) ? Bh : Bl;
        grow = (arr < 2) ? row0 : col0;
      } else {
        src = (arr == 0) ? Ah : Bh;
        grow = (arr == 0) ? row0 : col0;
      }
      gload16(src + (grow + (size_t)(mh * 64 + lane)) * (size_t)K + (size_t)(k0 + 8 * gg),
              &lds[buf][arr * 4096 + gg * 1024 + mh * 512]);
    }
  };

  STAGE(0, 0);
  __syncthreads();  // drain prologue loads
  int cur = 0;
  for (int k0 = 0; k0 < K; k0 += 32) {
    if (k0 + 32 < K) STAGE(cur ^ 1, k0 + 32);  // prefetch next tile (latency hides under compute)
    short8 ah[4], bh[4], al[4], bl[4];
#pragma unroll
    for (int mb = 0; mb < 4; ++mb) {
      ah[mb] = *(const short8*)&lds[cur][0 * 4096 + aoff + mb * 128];
      if (SPLIT) al[mb] = *(const short8*)&lds[cur][1 * 4096 + aoff + mb * 128];
    }
#pragma unroll
    for (int nb = 0; nb < 4; ++nb) {
      bh[nb] = *(const short8*)&lds[cur][(SPLIT ? 2 : 1) * 4096 + boff + nb * 128];
      if (SPLIT) bl[nb] = *(const short8*)&lds[cur][3 * 4096 + boff + nb * 128];
    }
#pragma unroll
    for (int mb = 0; mb < 4; ++mb)
#pragma unroll
      for (int nb = 0; nb < 4; ++nb) {
        acc[mb][nb] = __builtin_amdgcn_mfma_f32_16x16x32_bf16(ah[mb], bh[nb], acc[mb][nb], 0, 0, 0);
        if (SPLIT) {
          acc[mb][nb] = __builtin_amdgcn_mfma_f32_16x16x32_bf16(ah[mb], bl[nb], acc[mb][nb], 0, 0, 0);
          acc[mb][nb] = __builtin_amdgcn_mfma_f32_16x16x32_bf16(al[mb], bh[nb], acc[mb][nb], 0, 0, 0);
        }
      }
    __syncthreads();  // one barrier per K-step: drains prefetch, protects lds[cur] reads
    cur ^= 1;
  }
  // C/D layout (HW-verified): col = lane&15, row = (lane>>4)*4 + reg
#pragma unroll
  for (int mb = 0; mb < 4; ++mb)
#pragma unroll
    for (int nb = 0; nb < 4; ++nb) {
      size_t row = row0 + wr * 64 + mb * 16 + (lane >> 4) * 4;
      size_t col = col0 + wc * 64 + nb * 16 + r16;
      float* cp = C + row * (size_t)N + col;
#pragma unroll
      for (int r = 0; r < 4; ++r) cp[(size_t)r * N] = acc[mb][nb][r];
    }
}

// ---------- scan constants ----------
#define SB 4
#define ST 4096
#define SE 2048
#define CHUNK 64
#define NCHUNK 64
#define NCHAIN (SB * SE)  // 8192

// K2: elementwise transforms + chunk-local scan (from -inf) + chunk summaries.
// Overwrites proj in place: slot e <- lv, slot E+e <- lc.
__global__ __launch_bounds__(256) void k_scan1(float* __restrict__ proj,
                                               const float* __restrict__ bfv,
                                               float* __restrict__ Ac,
                                               float* __restrict__ Bc) {
  int idx = blockIdx.x * 256 + threadIdx.x;  // (c, b, e) with e fastest
  int e = idx & (SE - 1), b = (idx >> 11) & 3, c = idx >> 13;
  const float bk = bfv[e], bh = bfv[SE + e];
  float A = 0.f, S = -INFINITY;
  size_t base = ((size_t)(b * ST + c * CHUNK) * (2 * SE)) + e;
  for (int i = 0; i < CHUNK; ++i) {
    float k = proj[base] + bk;
    float hx = proj[base + SE] + bh;
    float sp = fmaxf(k, 0.f) + log1pf(expf(-fabsf(k)));  // softplus(k)
    float lc = -sp;                                      // log(1-sigmoid(k))
    float lg = (hx >= 0.f) ? logf(hx + 0.5f) : (hx - log1pf(expf(hx)));
    float lv = lg + k + lc;                              // log_g + log_sigmoid(k)
    A += lc;
    float a1 = lc + S;
    float m = fmaxf(a1, lv);
    S = m + log1pf(expf(fminf(a1, lv) - m));
    proj[base] = lv;
    proj[base + SE] = lc;
    base += 2 * SE;
  }
  int chain = b * SE + e;
  Ac[(size_t)c * NCHAIN + chain] = A;
  Bc[(size_t)c * NCHAIN + chain] = S;
}

// K3: scan over chunk summaries -> incoming state per chunk
__global__ __launch_bounds__(256) void k_scan2(const float* __restrict__ lh0,
                                               const float* __restrict__ Ac,
                                               const float* __restrict__ Bc,
                                               float* __restrict__ Hin) {
  int chain = blockIdx.x * 256 + threadIdx.x;  // 8192 = b*E + e
  float H = lh0[chain];
  for (int c = 0; c < NCHUNK; ++c) {
    Hin[(size_t)c * NCHAIN + chain] = H;
    float a = Ac[(size_t)c * NCHAIN + chain] + H;
    float bv = Bc[(size_t)c * NCHAIN + chain];
    float m = fmaxf(a, bv);
    H = m + log1pf(expf(fminf(a, bv) - m));
  }
}

// K4: replay scan with true incoming state; emit h_t (bf16) and out2 slices (f32)
__global__ __launch_bounds__(256) void k_scan3(const float* __restrict__ proj,
                                               const float* __restrict__ Hin,
                                               unsigned short* __restrict__ ht,
                                               float* __restrict__ out2) {
  int idx = blockIdx.x * 256 + threadIdx.x;
  int e = idx & (SE - 1), b = (idx >> 11) & 3, c = idx >> 13;
  float S = Hin[(size_t)c * NCHAIN + b * SE + e];
  size_t base = ((size_t)(b * ST + c * CHUNK) * (2 * SE)) + e;
  int t = c * CHUNK;
  size_t hto = ((size_t)(b * ST + t) * SE) + e;
  for (int i = 0; i < CHUNK; ++i, ++t) {
    float lv = proj[base], lc = proj[base + SE];
    float a1 = lc + S;
    float m = fmaxf(a1, lv);
    S = m + log1pf(expf(fminf(a1, lv) - m));
    ht[hto] = f2bf(expf(S));
    if (t >= 2 && ((t - 2) % 3) == 0) {   // t in {2,5,...,4094}
      int j = (t - 2) / 3;
      out2[((size_t)b * 1365 + j) * SE + e] = S;
    }
    base += 2 * SE;
    hto += SE;
  }
}

// ---------- launch ----------
extern "C" void kernel_launch(void* const* d_in, const int* in_sizes, int n_in,
                              void* d_out, int out_size, void* d_ws, size_t ws_size,
                              hipStream_t stream) {
  const float* x   = (const float*)d_in[0];
  const float* lh0 = (const float*)d_in[1];
  const float* wf  = (const float*)d_in[2];
  const float* bfv = (const float*)d_in[3];
  const float* wd  = (const float*)d_in[4];
  float* out1 = (float*)d_out;
  float* out2 = out1 + (size_t)SB * ST * 1024;

  char* p = (char*)d_ws;
  float* proj          = (float*)p;          p += 16384ull * 4096 * 4;  // 268 MB
  unsigned short* xhi  = (unsigned short*)p; p += 16384ull * 1024 * 2;
  unsigned short* xlo  = (unsigned short*)p; p += 16384ull * 1024 * 2;
  unsigned short* wfh  = (unsigned short*)p; p += 4096ull * 1024 * 2;
  unsigned short* wfl  = (unsigned short*)p; p += 4096ull * 1024 * 2;
  unsigned short* wdt  = (unsigned short*)p; p += 1024ull * 2048 * 2;
  unsigned short* ht   = (unsigned short*)p; p += 16384ull * 2048 * 2;  // 67 MB
  float* Ac            = (float*)p;          p += 64ull * 8192 * 4;
  float* Bc            = (float*)p;          p += 64ull * 8192 * 4;
  float* Hin           = (float*)p;          p += 64ull * 8192 * 4;

  // pre-passes
  hipLaunchKernelGGL(k_split, dim3(16384), dim3(256), 0, stream, x, xhi, xlo);
  hipLaunchKernelGGL((k_transpose<true>),  dim3(128, 32), dim3(256), 0, stream, wf, wfh, wfl, 1024, 4096);
  hipLaunchKernelGGL((k_transpose<false>), dim3(32, 64),  dim3(256), 0, stream, wd, wdt, nullptr, 2048, 1024);
  // GEMM1 (split-bf16, ~f32 accuracy): proj = x @ w_f
  hipLaunchKernelGGL((k_gemm<true>), dim3(128, 32), dim3(256), 0, stream,
                     xhi, xlo, wfh, wfl, proj, 16384, 4096, 1024);
  // 3-pass chunked log-space scan
  hipLaunchKernelGGL(k_scan1, dim3(2048), dim3(256), 0, stream, proj, bfv, Ac, Bc);
  hipLaunchKernelGGL(k_scan2, dim3(32), dim3(256), 0, stream, lh0, Ac, Bc, Hin);
  hipLaunchKernelGGL(k_scan3, dim3(2048), dim3(256), 0, stream, proj, Hin, ht, out2);
  // GEMM2 (bf16): out1 = h_t @ w_down
  hipLaunchKernelGGL((k_gemm<false>), dim3(128, 8), dim3(256), 0, stream,
                     ht, nullptr, wdt, nullptr, out1, 16384, 1024, 2048);
}

// Round 3
// 1020.152 us; speedup vs baseline: 1.6934x; 1.6739x over previous
//
#include <hip/hip_runtime.h>
#include <cstdint>
#include <cstddef>

typedef __attribute__((ext_vector_type(4))) float f32x4;
typedef __attribute__((ext_vector_type(8))) short short8;

// ---------- bf16 helpers (bit-level, header-version independent) ----------
__device__ __forceinline__ unsigned short f2bf(float f) {
  unsigned int u = __float_as_uint(f);
  u += 0x7fffu + ((u >> 16) & 1u);            // round to nearest even
  return (unsigned short)(u >> 16);
}
__device__ __forceinline__ float bf2f(unsigned short h) {
  return __uint_as_float(((unsigned int)h) << 16);
}

__device__ __forceinline__ void gload16(const unsigned short* g, unsigned short* l) {
  __builtin_amdgcn_global_load_lds(
      (const __attribute__((address_space(1))) void*)g,
      (__attribute__((address_space(3))) void*)l, 16, 0, 0);
}

// ---------- P1: split x f32 -> bf16 hi + lo ----------
__global__ __launch_bounds__(256) void k_split(const float* __restrict__ src,
                                               unsigned short* __restrict__ hi,
                                               unsigned short* __restrict__ lo) {
  size_t i = ((size_t)blockIdx.x * 256 + threadIdx.x) * 4;
  float4 v = *(const float4*)(src + i);
  unsigned short h0 = f2bf(v.x), h1 = f2bf(v.y), h2 = f2bf(v.z), h3 = f2bf(v.w);
  ushort4 hv = make_ushort4(h0, h1, h2, h3);
  ushort4 lv = make_ushort4(f2bf(v.x - bf2f(h0)), f2bf(v.y - bf2f(h1)),
                            f2bf(v.z - bf2f(h2)), f2bf(v.w - bf2f(h3)));
  *(ushort4*)(hi + i) = hv;
  *(ushort4*)(lo + i) = lv;
}

// ---------- P2/P3: transpose f32 [R][C] -> bf16 [C][R] (optionally split) ----------
template<bool SPLIT>
__global__ __launch_bounds__(256) void k_transpose(const float* __restrict__ src,
                                                   unsigned short* __restrict__ hi,
                                                   unsigned short* __restrict__ lo,
                                                   int R, int C) {
  __shared__ float tile[32][33];
  int tx = threadIdx.x & 31, ty = threadIdx.x >> 5;  // ty 0..7
  int c0 = blockIdx.x * 32, r0 = blockIdx.y * 32;
#pragma unroll
  for (int i = 0; i < 4; ++i)
    tile[ty + 8 * i][tx] = src[(size_t)(r0 + ty + 8 * i) * C + (c0 + tx)];
  __syncthreads();
#pragma unroll
  for (int i = 0; i < 4; ++i) {
    float v = tile[tx][ty + 8 * i];
    size_t o = (size_t)(c0 + ty + 8 * i) * R + (r0 + tx);
    unsigned short h = f2bf(v);
    hi[o] = h;
    if (SPLIT) lo[o] = f2bf(v - bf2f(h));
  }
}

// ---------- GEMM: A[M][K] (bf16, k-contig), B[N][K] (bf16, k-contig) -> C[M][N] f32
// 128x128 tile, BK=32, 4 waves, double-buffered prefetch.
// LDS layout per array: row-major [128 rows][32 k] (64B rows).
// STAGE: instr covers 16 rows; lane l -> row l>>2, k-byte (l&3)*16: each 4-lane
// group reads one contiguous 64B line -> 16 line-requests/instr (was 64 sub-line
// requests/instr in the slot-major layout = TA-saturated, MfmaUtil 15%).
// Fragment read: lane l -> row r16=l&15, k-slot l>>4 (same lane->(row,k) map as the
// verified kernel; A/B symmetric so contraction convention unchanged); each wave
// reads a contiguous 1KB block -> conflict-free.
// SPLIT: acc += Ah*Bh + Ah*Bl + Al*Bh  (split-bf16 ~f32 precision)
template<bool SPLIT>
__global__ __launch_bounds__(256) void k_gemm(const unsigned short* __restrict__ Ah,
                                              const unsigned short* __restrict__ Al,
                                              const unsigned short* __restrict__ Bh,
                                              const unsigned short* __restrict__ Bl,
                                              float* __restrict__ C, int M, int N, int K) {
  constexpr int NARR = SPLIT ? 4 : 2;
  __shared__ unsigned short lds[2][NARR * 4096];
  const int tid = threadIdx.x, wave = tid >> 6, lane = tid & 63;
  const size_t row0 = (size_t)blockIdx.x * 128;
  const size_t col0 = (size_t)blockIdx.y * 128;
  const int wr = wave >> 1, wc = wave & 1;
  const int r16 = lane & 15;
  // fragment offsets (shorts): row*32 + kslot*8
  const int aoff = (wr * 64 + r16) * 32 + (lane >> 4) * 8;
  const int boff = (wc * 64 + r16) * 32 + (lane >> 4) * 8;

  f32x4 acc[4][4];
#pragma unroll
  for (int i = 0; i < 4; ++i)
#pragma unroll
    for (int j = 0; j < 4; ++j) acc[i][j] = (f32x4){0.f, 0.f, 0.f, 0.f};

  // stage one K-step (BK=32) of all NARR arrays into lds[buf]
  auto STAGE = [&](int buf, int k0) {
#pragma unroll
    for (int i = 0; i < NARR * 2; ++i) {
      int L = wave * (NARR * 2) + i;
      int arr = L >> 3, inst = L & 7;          // 8 instrs per array, 16 rows each
      const unsigned short* src;
      size_t grow;
      if (SPLIT) {
        src = (arr == 0) ? Ah : (arr == 1) ? Al : (arr == 2) ? Bh : Bl;
        grow = (arr < 2) ? row0 : col0;
      } else {
        src = (arr == 0) ? Ah : Bh;
        grow = (arr == 0) ? row0 : col0;
      }
      // lane l: row = inst*16 + (l>>2), k-offset (l&3)*8 shorts (16B) -> one 64B line per 4 lanes
      gload16(src + (grow + (size_t)(inst * 16 + (lane >> 2))) * (size_t)K
                  + (size_t)(k0 + (lane & 3) * 8),
              &lds[buf][arr * 4096 + inst * 512]);
    }
  };

  STAGE(0, 0);
  __syncthreads();  // drain prologue loads
  int cur = 0;
  for (int k0 = 0; k0 < K; k0 += 32) {
    if (k0 + 32 < K) STAGE(cur ^ 1, k0 + 32);  // prefetch next tile
    short8 ah[4], bh[4], al[4], bl[4];
#pragma unroll
    for (int mb = 0; mb < 4; ++mb) {
      ah[mb] = *(const short8*)&lds[cur][0 * 4096 + aoff + mb * 512];
      if (SPLIT) al[mb] = *(const short8*)&lds[cur][1 * 4096 + aoff + mb * 512];
    }
#pragma unroll
    for (int nb = 0; nb < 4; ++nb) {
      bh[nb] = *(const short8*)&lds[cur][(SPLIT ? 2 : 1) * 4096 + boff + nb * 512];
      if (SPLIT) bl[nb] = *(const short8*)&lds[cur][3 * 4096 + boff + nb * 512];
    }
#pragma unroll
    for (int mb = 0; mb < 4; ++mb)
#pragma unroll
      for (int nb = 0; nb < 4; ++nb) {
        acc[mb][nb] = __builtin_amdgcn_mfma_f32_16x16x32_bf16(ah[mb], bh[nb], acc[mb][nb], 0, 0, 0);
        if (SPLIT) {
          acc[mb][nb] = __builtin_amdgcn_mfma_f32_16x16x32_bf16(ah[mb], bl[nb], acc[mb][nb], 0, 0, 0);
          acc[mb][nb] = __builtin_amdgcn_mfma_f32_16x16x32_bf16(al[mb], bh[nb], acc[mb][nb], 0, 0, 0);
        }
      }
    __syncthreads();  // one barrier per K-step: drains prefetch, protects lds[cur] reads
    cur ^= 1;
  }
  // C/D layout (HW-verified): col = lane&15, row = (lane>>4)*4 + reg
#pragma unroll
  for (int mb = 0; mb < 4; ++mb)
#pragma unroll
    for (int nb = 0; nb < 4; ++nb) {
      size_t row = row0 + wr * 64 + mb * 16 + (lane >> 4) * 4;
      size_t col = col0 + wc * 64 + nb * 16 + r16;
      float* cp = C + row * (size_t)N + col;
#pragma unroll
      for (int r = 0; r < 4; ++r) cp[(size_t)r * N] = acc[mb][nb][r];
    }
}

// ---------- scan constants ----------
#define SB 4
#define ST 4096
#define SE 2048
#define CHUNK 64
#define NCHUNK 64
#define NCHAIN (SB * SE)  // 8192

// K2: elementwise transforms + chunk-local scan (from -inf) + chunk summaries.
// Overwrites proj in place: slot e <- lv, slot E+e <- lc.
__global__ __launch_bounds__(256) void k_scan1(float* __restrict__ proj,
                                               const float* __restrict__ bfv,
                                               float* __restrict__ Ac,
                                               float* __restrict__ Bc) {
  int idx = blockIdx.x * 256 + threadIdx.x;  // (c, b, e) with e fastest
  int e = idx & (SE - 1), b = (idx >> 11) & 3, c = idx >> 13;
  const float bk = bfv[e], bh = bfv[SE + e];
  float A = 0.f, S = -INFINITY;
  size_t base = ((size_t)(b * ST + c * CHUNK) * (2 * SE)) + e;
  for (int i = 0; i < CHUNK; ++i) {
    float k = proj[base] + bk;
    float hx = proj[base + SE] + bh;
    float sp = fmaxf(k, 0.f) + log1pf(expf(-fabsf(k)));  // softplus(k)
    float lc = -sp;                                      // log(1-sigmoid(k))
    float lg = (hx >= 0.f) ? logf(hx + 0.5f) : (hx - log1pf(expf(hx)));
    float lv = lg + k + lc;                              // log_g + log_sigmoid(k)
    A += lc;
    float a1 = lc + S;
    float m = fmaxf(a1, lv);
    S = m + log1pf(expf(fminf(a1, lv) - m));
    proj[base] = lv;
    proj[base + SE] = lc;
    base += 2 * SE;
  }
  int chain = b * SE + e;
  Ac[(size_t)c * NCHAIN + chain] = A;
  Bc[(size_t)c * NCHAIN + chain] = S;
}

// K3: scan over chunk summaries -> incoming state per chunk
__global__ __launch_bounds__(256) void k_scan2(const float* __restrict__ lh0,
                                               const float* __restrict__ Ac,
                                               const float* __restrict__ Bc,
                                               float* __restrict__ Hin) {
  int chain = blockIdx.x * 256 + threadIdx.x;  // 8192 = b*E + e
  float H = lh0[chain];
  for (int c = 0; c < NCHUNK; ++c) {
    Hin[(size_t)c * NCHAIN + chain] = H;
    float a = Ac[(size_t)c * NCHAIN + chain] + H;
    float bv = Bc[(size_t)c * NCHAIN + chain];
    float m = fmaxf(a, bv);
    H = m + log1pf(expf(fminf(a, bv) - m));
  }
}

// K4: replay scan with true incoming state; emit h_t (bf16) and out2 slices (f32)
__global__ __launch_bounds__(256) void k_scan3(const float* __restrict__ proj,
                                               const float* __restrict__ Hin,
                                               unsigned short* __restrict__ ht,
                                               float* __restrict__ out2) {
  int idx = blockIdx.x * 256 + threadIdx.x;
  int e = idx & (SE - 1), b = (idx >> 11) & 3, c = idx >> 13;
  float S = Hin[(size_t)c * NCHAIN + b * SE + e];
  size_t base = ((size_t)(b * ST + c * CHUNK) * (2 * SE)) + e;
  int t = c * CHUNK;
  size_t hto = ((size_t)(b * ST + t) * SE) + e;
  for (int i = 0; i < CHUNK; ++i, ++t) {
    float lv = proj[base], lc = proj[base + SE];
    float a1 = lc + S;
    float m = fmaxf(a1, lv);
    S = m + log1pf(expf(fminf(a1, lv) - m));
    ht[hto] = f2bf(expf(S));
    if (t >= 2 && ((t - 2) % 3) == 0) {   // t in {2,5,...,4094}
      int j = (t - 2) / 3;
      out2[((size_t)b * 1365 + j) * SE + e] = S;
    }
    base += 2 * SE;
    hto += SE;
  }
}

// ---------- launch ----------
extern "C" void kernel_launch(void* const* d_in, const int* in_sizes, int n_in,
                              void* d_out, int out_size, void* d_ws, size_t ws_size,
                              hipStream_t stream) {
  const float* x   = (const float*)d_in[0];
  const float* lh0 = (const float*)d_in[1];
  const float* wf  = (const float*)d_in[2];
  const float* bfv = (const float*)d_in[3];
  const float* wd  = (const float*)d_in[4];
  float* out1 = (float*)d_out;
  float* out2 = out1 + (size_t)SB * ST * 1024;

  char* p = (char*)d_ws;
  float* proj          = (float*)p;          p += 16384ull * 4096 * 4;  // 268 MB
  unsigned short* xhi  = (unsigned short*)p; p += 16384ull * 1024 * 2;
  unsigned short* xlo  = (unsigned short*)p; p += 16384ull * 1024 * 2;
  unsigned short* wfh  = (unsigned short*)p; p += 4096ull * 1024 * 2;
  unsigned short* wfl  = (unsigned short*)p; p += 4096ull * 1024 * 2;
  unsigned short* wdt  = (unsigned short*)p; p += 1024ull * 2048 * 2;
  unsigned short* ht   = (unsigned short*)p; p += 16384ull * 2048 * 2;  // 67 MB
  float* Ac            = (float*)p;          p += 64ull * 8192 * 4;
  float* Bc            = (float*)p;          p += 64ull * 8192 * 4;
  float* Hin           = (float*)p;          p += 64ull * 8192 * 4;

  // pre-passes
  hipLaunchKernelGGL(k_split, dim3(16384), dim3(256), 0, stream, x, xhi, xlo);
  hipLaunchKernelGGL((k_transpose<true>),  dim3(128, 32), dim3(256), 0, stream, wf, wfh, wfl, 1024, 4096);
  hipLaunchKernelGGL((k_transpose<false>), dim3(32, 64),  dim3(256), 0, stream, wd, wdt, nullptr, 2048, 1024);
  // GEMM1 (split-bf16, ~f32 accuracy): proj = x @ w_f
  hipLaunchKernelGGL((k_gemm<true>), dim3(128, 32), dim3(256), 0, stream,
                     xhi, xlo, wfh, wfl, proj, 16384, 4096, 1024);
  // 3-pass chunked log-space scan
  hipLaunchKernelGGL(k_scan1, dim3(2048), dim3(256), 0, stream, proj, bfv, Ac, Bc);
  hipLaunchKernelGGL(k_scan2, dim3(32), dim3(256), 0, stream, lh0, Ac, Bc, Hin);
  hipLaunchKernelGGL(k_scan3, dim3(2048), dim3(256), 0, stream, proj, Hin, ht, out2);
  // GEMM2 (bf16): out1 = h_t @ w_down
  hipLaunchKernelGGL((k_gemm<false>), dim3(128, 8), dim3(256), 0, stream,
                     ht, nullptr, wdt, nullptr, out1, 16384, 1024, 2048);
}

// Round 4
// 777.548 us; speedup vs baseline: 2.2218x; 1.3120x over previous
//
#include <hip/hip_runtime.h>
#include <cstdint>
#include <cstddef>

typedef __attribute__((ext_vector_type(4))) float f32x4;
typedef __attribute__((ext_vector_type(8))) short short8;

// ---------- bf16 helpers (bit-level, header-version independent) ----------
__device__ __forceinline__ unsigned short f2bf(float f) {
  unsigned int u = __float_as_uint(f);
  u += 0x7fffu + ((u >> 16) & 1u);            // round to nearest even
  return (unsigned short)(u >> 16);
}
__device__ __forceinline__ float bf2f(unsigned short h) {
  return __uint_as_float(((unsigned int)h) << 16);
}

__device__ __forceinline__ void gload16(const unsigned short* g, unsigned short* l) {
  __builtin_amdgcn_global_load_lds(
      (const __attribute__((address_space(1))) void*)g,
      (__attribute__((address_space(3))) void*)l, 16, 0, 0);
}

// ---------- P1: x f32 -> bf16 ----------
__global__ __launch_bounds__(256) void k_cast(const float* __restrict__ src,
                                              unsigned short* __restrict__ hi) {
  size_t i = ((size_t)blockIdx.x * 256 + threadIdx.x) * 4;
  float4 v = *(const float4*)(src + i);
  *(ushort4*)(hi + i) = make_ushort4(f2bf(v.x), f2bf(v.y), f2bf(v.z), f2bf(v.w));
}

// ---------- P2/P3: transpose f32 [R][C] -> bf16 [C][R] ----------
__global__ __launch_bounds__(256) void k_transpose(const float* __restrict__ src,
                                                   unsigned short* __restrict__ hi,
                                                   int R, int C) {
  __shared__ float tile[32][33];
  int tx = threadIdx.x & 31, ty = threadIdx.x >> 5;  // ty 0..7
  int c0 = blockIdx.x * 32, r0 = blockIdx.y * 32;
#pragma unroll
  for (int i = 0; i < 4; ++i)
    tile[ty + 8 * i][tx] = src[(size_t)(r0 + ty + 8 * i) * C + (c0 + tx)];
  __syncthreads();
#pragma unroll
  for (int i = 0; i < 4; ++i) {
    float v = tile[tx][ty + 8 * i];
    hi[(size_t)(c0 + ty + 8 * i) * R + (r0 + tx)] = f2bf(v);
  }
}

// ---------- GEMM: A[M][K] (bf16, k-contig), B[N][K] (bf16, k-contig) -> C[M][N] f32
// 128x128 tile, BK=32, 4 waves, double-buffered prefetch.
// LDS per array: row-major [128 rows][32 k] (64B rows), k-slot XOR-swizzled:
//   position (row, slot ks) holds k-chunk (ks ^ ((row>>1)&3)).
// STAGE keeps a LINEAR LDS dest (global_load_lds requirement) and pre-swizzles the
// GLOBAL k-offset per lane; each 4-lane group still reads one contiguous 64B line
// (TA-friendly: 16 line-requests/instr). Fragment read applies the same XOR ->
// per-16-lane phase every 16B bank-slot is hit exactly 2x (2-way = free, m136).
// Was: 8-way conflict, SQ_LDS_BANK_CONFLICT=3.35e7.
__global__ __launch_bounds__(256) void k_gemm(const unsigned short* __restrict__ A,
                                              const unsigned short* __restrict__ B,
                                              float* __restrict__ C, int M, int N, int K) {
  __shared__ unsigned short lds[2][2 * 4096];
  const int tid = threadIdx.x, wave = tid >> 6, lane = tid & 63;
  const size_t row0 = (size_t)blockIdx.x * 128;
  const size_t col0 = (size_t)blockIdx.y * 128;
  const int wr = wave >> 1, wc = wave & 1;
  const int r16 = lane & 15;
  const int ksw = ((lane >> 4) ^ ((r16 >> 1) & 3));  // swizzled k-slot for fragment reads
  // fragment offsets (shorts): row*32 + ksw*8
  const int aoff = (wr * 64 + r16) * 32 + ksw * 8;
  const int boff = (wc * 64 + r16) * 32 + ksw * 8;
  const int gks = ((lane & 3) ^ ((lane >> 3) & 3)) * 8;  // pre-swizzled global k-offset (shorts)

  f32x4 acc[4][4];
#pragma unroll
  for (int i = 0; i < 4; ++i)
#pragma unroll
    for (int j = 0; j < 4; ++j) acc[i][j] = (f32x4){0.f, 0.f, 0.f, 0.f};

  // stage one K-step (BK=32) of A and B into lds[buf]
  auto STAGE = [&](int buf, int k0) {
#pragma unroll
    for (int i = 0; i < 4; ++i) {
      int L = wave * 4 + i;
      int arr = L >> 3, inst = L & 7;          // 8 instrs per array, 16 rows each
      const unsigned short* src = (arr == 0) ? A : B;
      size_t grow = (arr == 0) ? row0 : col0;
      // lane l: row = inst*16 + (l>>2); global k pre-swizzled so linear LDS dest ends up swizzled
      gload16(src + (grow + (size_t)(inst * 16 + (lane >> 2))) * (size_t)K
                  + (size_t)(k0 + gks),
              &lds[buf][arr * 4096 + inst * 512]);
    }
  };

  STAGE(0, 0);
  __syncthreads();  // drain prologue loads
  int cur = 0;
  for (int k0 = 0; k0 < K; k0 += 32) {
    if (k0 + 32 < K) STAGE(cur ^ 1, k0 + 32);  // prefetch next tile
    short8 ah[4], bh[4];
#pragma unroll
    for (int mb = 0; mb < 4; ++mb)
      ah[mb] = *(const short8*)&lds[cur][0 * 4096 + aoff + mb * 512];
#pragma unroll
    for (int nb = 0; nb < 4; ++nb)
      bh[nb] = *(const short8*)&lds[cur][1 * 4096 + boff + nb * 512];
#pragma unroll
    for (int mb = 0; mb < 4; ++mb)
#pragma unroll
      for (int nb = 0; nb < 4; ++nb)
        acc[mb][nb] = __builtin_amdgcn_mfma_f32_16x16x32_bf16(ah[mb], bh[nb], acc[mb][nb], 0, 0, 0);
    __syncthreads();  // one barrier per K-step: drains prefetch, protects lds[cur] reads
    cur ^= 1;
  }
  // C/D layout (HW-verified): col = lane&15, row = (lane>>4)*4 + reg
#pragma unroll
  for (int mb = 0; mb < 4; ++mb)
#pragma unroll
    for (int nb = 0; nb < 4; ++nb) {
      size_t row = row0 + wr * 64 + mb * 16 + (lane >> 4) * 4;
      size_t col = col0 + wc * 64 + nb * 16 + r16;
      float* cp = C + row * (size_t)N + col;
#pragma unroll
      for (int r = 0; r < 4; ++r) cp[(size_t)r * N] = acc[mb][nb][r];
    }
}

// ---------- scan constants ----------
#define SB 4
#define ST 4096
#define SE 2048
#define CHUNK 64
#define NCHUNK 64
#define NCHAIN (SB * SE)  // 8192

// K2: elementwise transforms + chunk-local scan (from -inf) + chunk summaries.
// Overwrites proj in place: slot e <- lv, slot E+e <- lc.
__global__ __launch_bounds__(256) void k_scan1(float* __restrict__ proj,
                                               const float* __restrict__ bfv,
                                               float* __restrict__ Ac,
                                               float* __restrict__ Bc) {
  int idx = blockIdx.x * 256 + threadIdx.x;  // (c, b, e) with e fastest
  int e = idx & (SE - 1), b = (idx >> 11) & 3, c = idx >> 13;
  const float bk = bfv[e], bh = bfv[SE + e];
  float A = 0.f, S = -INFINITY;
  size_t base = ((size_t)(b * ST + c * CHUNK) * (2 * SE)) + e;
  for (int i = 0; i < CHUNK; ++i) {
    float k = proj[base] + bk;
    float hx = proj[base + SE] + bh;
    float sp = fmaxf(k, 0.f) + log1pf(expf(-fabsf(k)));  // softplus(k)
    float lc = -sp;                                      // log(1-sigmoid(k))
    float lg = (hx >= 0.f) ? logf(hx + 0.5f) : (hx - log1pf(expf(hx)));
    float lv = lg + k + lc;                              // log_g + log_sigmoid(k)
    A += lc;
    float a1 = lc + S;
    float m = fmaxf(a1, lv);
    S = m + log1pf(expf(fminf(a1, lv) - m));
    proj[base] = lv;
    proj[base + SE] = lc;
    base += 2 * SE;
  }
  int chain = b * SE + e;
  Ac[(size_t)c * NCHAIN + chain] = A;
  Bc[(size_t)c * NCHAIN + chain] = S;
}

// K3: scan over chunk summaries -> incoming state per chunk
__global__ __launch_bounds__(256) void k_scan2(const float* __restrict__ lh0,
                                               const float* __restrict__ Ac,
                                               const float* __restrict__ Bc,
                                               float* __restrict__ Hin) {
  int chain = blockIdx.x * 256 + threadIdx.x;  // 8192 = b*E + e
  float H = lh0[chain];
  for (int c = 0; c < NCHUNK; ++c) {
    Hin[(size_t)c * NCHAIN + chain] = H;
    float a = Ac[(size_t)c * NCHAIN + chain] + H;
    float bv = Bc[(size_t)c * NCHAIN + chain];
    float m = fmaxf(a, bv);
    H = m + log1pf(expf(fminf(a, bv) - m));
  }
}

// K4: replay scan with true incoming state; emit h_t (bf16) and out2 slices (f32)
__global__ __launch_bounds__(256) void k_scan3(const float* __restrict__ proj,
                                               const float* __restrict__ Hin,
                                               unsigned short* __restrict__ ht,
                                               float* __restrict__ out2) {
  int idx = blockIdx.x * 256 + threadIdx.x;
  int e = idx & (SE - 1), b = (idx >> 11) & 3, c = idx >> 13;
  float S = Hin[(size_t)c * NCHAIN + b * SE + e];
  size_t base = ((size_t)(b * ST + c * CHUNK) * (2 * SE)) + e;
  int t = c * CHUNK;
  size_t hto = ((size_t)(b * ST + t) * SE) + e;
  for (int i = 0; i < CHUNK; ++i, ++t) {
    float lv = proj[base], lc = proj[base + SE];
    float a1 = lc + S;
    float m = fmaxf(a1, lv);
    S = m + log1pf(expf(fminf(a1, lv) - m));
    ht[hto] = f2bf(expf(S));
    if (t >= 2 && ((t - 2) % 3) == 0) {   // t in {2,5,...,4094}
      int j = (t - 2) / 3;
      out2[((size_t)b * 1365 + j) * SE + e] = S;
    }
    base += 2 * SE;
    hto += SE;
  }
}

// ---------- launch ----------
extern "C" void kernel_launch(void* const* d_in, const int* in_sizes, int n_in,
                              void* d_out, int out_size, void* d_ws, size_t ws_size,
                              hipStream_t stream) {
  const float* x   = (const float*)d_in[0];
  const float* lh0 = (const float*)d_in[1];
  const float* wf  = (const float*)d_in[2];
  const float* bfv = (const float*)d_in[3];
  const float* wd  = (const float*)d_in[4];
  float* out1 = (float*)d_out;
  float* out2 = out1 + (size_t)SB * ST * 1024;

  char* p = (char*)d_ws;
  float* proj          = (float*)p;          p += 16384ull * 4096 * 4;  // 268 MB
  unsigned short* xhi  = (unsigned short*)p; p += 16384ull * 1024 * 2;
  unsigned short* wfh  = (unsigned short*)p; p += 4096ull * 1024 * 2;
  unsigned short* wdt  = (unsigned short*)p; p += 1024ull * 2048 * 2;
  unsigned short* ht   = (unsigned short*)p; p += 16384ull * 2048 * 2;  // 67 MB
  float* Ac            = (float*)p;          p += 64ull * 8192 * 4;
  float* Bc            = (float*)p;          p += 64ull * 8192 * 4;
  float* Hin           = (float*)p;          p += 64ull * 8192 * 4;

  // pre-passes
  hipLaunchKernelGGL(k_cast, dim3(16384), dim3(256), 0, stream, x, xhi);
  hipLaunchKernelGGL(k_transpose, dim3(128, 32), dim3(256), 0, stream, wf, wfh, 1024, 4096);
  hipLaunchKernelGGL(k_transpose, dim3(32, 64),  dim3(256), 0, stream, wd, wdt, 2048, 1024);
  // GEMM1 (bf16): proj = x @ w_f
  hipLaunchKernelGGL(k_gemm, dim3(128, 32), dim3(256), 0, stream,
                     xhi, wfh, proj, 16384, 4096, 1024);
  // 3-pass chunked log-space scan
  hipLaunchKernelGGL(k_scan1, dim3(2048), dim3(256), 0, stream, proj, bfv, Ac, Bc);
  hipLaunchKernelGGL(k_scan2, dim3(32), dim3(256), 0, stream, lh0, Ac, Bc, Hin);
  hipLaunchKernelGGL(k_scan3, dim3(2048), dim3(256), 0, stream, proj, Hin, ht, out2);
  // GEMM2 (bf16): out1 = h_t @ w_down
  hipLaunchKernelGGL(k_gemm, dim3(128, 8), dim3(256), 0, stream,
                     ht, wdt, out1, 16384, 1024, 2048);
}

// Round 5
// 469.323 us; speedup vs baseline: 3.6809x; 1.6567x over previous
//
#include <hip/hip_runtime.h>
#include <cstdint>
#include <cstddef>

typedef __attribute__((ext_vector_type(4))) float f32x4;
typedef __attribute__((ext_vector_type(8))) short short8;

// ---------- bf16 helpers (bit-level, header-version independent) ----------
__device__ __forceinline__ unsigned short f2bf(float f) {
  unsigned int u = __float_as_uint(f);
  u += 0x7fffu + ((u >> 16) & 1u);            // round to nearest even
  return (unsigned short)(u >> 16);
}
__device__ __forceinline__ float bf2f(unsigned short h) {
  return __uint_as_float(((unsigned int)h) << 16);
}

__device__ __forceinline__ void gload16(const unsigned short* g, unsigned short* l) {
  __builtin_amdgcn_global_load_lds(
      (const __attribute__((address_space(1))) void*)g,
      (__attribute__((address_space(3))) void*)l, 16, 0, 0);
}

// ---------- P1: x f32 -> bf16 ----------
__global__ __launch_bounds__(256) void k_cast(const float* __restrict__ src,
                                              unsigned short* __restrict__ hi) {
  size_t i = ((size_t)blockIdx.x * 256 + threadIdx.x) * 4;
  float4 v = *(const float4*)(src + i);
  *(ushort4*)(hi + i) = make_ushort4(f2bf(v.x), f2bf(v.y), f2bf(v.z), f2bf(v.w));
}

// ---------- P2/P3: transpose f32 [R][C] -> bf16 [C][R] ----------
__global__ __launch_bounds__(256) void k_transpose(const float* __restrict__ src,
                                                   unsigned short* __restrict__ hi,
                                                   int R, int C) {
  __shared__ float tile[32][33];
  int tx = threadIdx.x & 31, ty = threadIdx.x >> 5;  // ty 0..7
  int c0 = blockIdx.x * 32, r0 = blockIdx.y * 32;
#pragma unroll
  for (int i = 0; i < 4; ++i)
    tile[ty + 8 * i][tx] = src[(size_t)(r0 + ty + 8 * i) * C + (c0 + tx)];
  __syncthreads();
#pragma unroll
  for (int i = 0; i < 4; ++i) {
    float v = tile[tx][ty + 8 * i];
    hi[(size_t)(c0 + ty + 8 * i) * R + (r0 + tx)] = f2bf(v);
  }
}

// ---------- GEMM: A[M][K] (bf16, k-contig), B[N][K] (bf16, k-contig) -> C[M][N] f32
// 128x128 tile, BK=32, 4 waves, double-buffered prefetch.
// LDS per array: row-major [128 rows][32 k] (64B rows), k-slot XOR-swizzled:
//   position (row, slot ks) holds k-chunk (ks ^ ((row>>1)&3)).
// STAGE keeps a LINEAR LDS dest (global_load_lds requirement) and pre-swizzles the
// GLOBAL k-offset per lane; each 4-lane group reads one contiguous 64B line
// (TA-friendly). Fragment read applies the same XOR -> 2-way (free) LDS access.
__global__ __launch_bounds__(256) void k_gemm(const unsigned short* __restrict__ A,
                                              const unsigned short* __restrict__ B,
                                              float* __restrict__ C, int M, int N, int K) {
  __shared__ unsigned short lds[2][2 * 4096];
  const int tid = threadIdx.x, wave = tid >> 6, lane = tid & 63;
  const size_t row0 = (size_t)blockIdx.x * 128;
  const size_t col0 = (size_t)blockIdx.y * 128;
  const int wr = wave >> 1, wc = wave & 1;
  const int r16 = lane & 15;
  const int ksw = ((lane >> 4) ^ ((r16 >> 1) & 3));  // swizzled k-slot for fragment reads
  const int aoff = (wr * 64 + r16) * 32 + ksw * 8;
  const int boff = (wc * 64 + r16) * 32 + ksw * 8;
  const int gks = ((lane & 3) ^ ((lane >> 3) & 3)) * 8;  // pre-swizzled global k-offset (shorts)

  f32x4 acc[4][4];
#pragma unroll
  for (int i = 0; i < 4; ++i)
#pragma unroll
    for (int j = 0; j < 4; ++j) acc[i][j] = (f32x4){0.f, 0.f, 0.f, 0.f};

  auto STAGE = [&](int buf, int k0) {
#pragma unroll
    for (int i = 0; i < 4; ++i) {
      int L = wave * 4 + i;
      int arr = L >> 3, inst = L & 7;          // 8 instrs per array, 16 rows each
      const unsigned short* src = (arr == 0) ? A : B;
      size_t grow = (arr == 0) ? row0 : col0;
      gload16(src + (grow + (size_t)(inst * 16 + (lane >> 2))) * (size_t)K
                  + (size_t)(k0 + gks),
              &lds[buf][arr * 4096 + inst * 512]);
    }
  };

  STAGE(0, 0);
  __syncthreads();
  int cur = 0;
  for (int k0 = 0; k0 < K; k0 += 32) {
    if (k0 + 32 < K) STAGE(cur ^ 1, k0 + 32);  // prefetch next tile
    short8 ah[4], bh[4];
#pragma unroll
    for (int mb = 0; mb < 4; ++mb)
      ah[mb] = *(const short8*)&lds[cur][0 * 4096 + aoff + mb * 512];
#pragma unroll
    for (int nb = 0; nb < 4; ++nb)
      bh[nb] = *(const short8*)&lds[cur][1 * 4096 + boff + nb * 512];
#pragma unroll
    for (int mb = 0; mb < 4; ++mb)
#pragma unroll
      for (int nb = 0; nb < 4; ++nb)
        acc[mb][nb] = __builtin_amdgcn_mfma_f32_16x16x32_bf16(ah[mb], bh[nb], acc[mb][nb], 0, 0, 0);
    __syncthreads();
    cur ^= 1;
  }
  // C/D layout (HW-verified): col = lane&15, row = (lane>>4)*4 + reg
#pragma unroll
  for (int mb = 0; mb < 4; ++mb)
#pragma unroll
    for (int nb = 0; nb < 4; ++nb) {
      size_t row = row0 + wr * 64 + mb * 16 + (lane >> 4) * 4;
      size_t col = col0 + wc * 64 + nb * 16 + r16;
      float* cp = C + row * (size_t)N + col;
#pragma unroll
      for (int r = 0; r < 4; ++r) cp[(size_t)r * N] = acc[mb][nb][r];
    }
}

// ---------- scan constants ----------
#define SB 4
#define ST 4096
#define SE 2048
#define CHUNK 64
#define NCHUNK 64
#define NCHAIN (SB * SE)  // 8192

// transforms via native v_exp_f32/v_log_f32 (__expf/__logf), ~1e-7 abs error in
// log-space (irrelevant vs 0.134 budget). Replaces libm log1pf/logf (~25-30 VALU
// ops each, was VALUBusy=107%).
__device__ __forceinline__ void transform(float k, float hx, float& lc, float& lv) {
  float u = __expf(-fabsf(k));
  float sp = fmaxf(k, 0.f) + __logf(1.f + u);   // softplus(k)
  lc = -sp;                                     // log(1 - sigmoid(k))
  float eh = __expf(fminf(hx, 0.f));            // exp(hx) for hx<0 (clamped: no overflow)
  float arg = (hx >= 0.f) ? (hx + 0.5f) : (1.f + eh);
  float vl = __logf(arg);
  float lg = (hx >= 0.f) ? vl : (hx - vl);      // log g(hx)
  lv = lg + k + lc;                             // log g + log sigmoid(k)
}
__device__ __forceinline__ float lse_step(float lc, float lv, float S) {
  float a1 = lc + S;
  float m = fmaxf(a1, lv);
  float d = fminf(a1, lv) - m;                  // <= 0 (or -inf)
  return m + __logf(1.f + __expf(d));
}

// K2: transforms + chunk-local scan (from -inf) -> chunk summaries ONLY.
// proj is read-only now (scan3 recomputes lv/lc): saves the 268 MB lv/lc write.
__global__ __launch_bounds__(256) void k_scan1(const float* __restrict__ proj,
                                               const float* __restrict__ bfv,
                                               float* __restrict__ Ac,
                                               float* __restrict__ Bc) {
  int idx = blockIdx.x * 256 + threadIdx.x;  // (c, b, e) with e fastest
  int e = idx & (SE - 1), b = (idx >> 11) & 3, c = idx >> 13;
  const float bk = bfv[e], bh = bfv[SE + e];
  float A = 0.f, S = -INFINITY;
  size_t base = ((size_t)(b * ST + c * CHUNK) * (2 * SE)) + e;
  for (int i = 0; i < CHUNK; ++i) {
    float lc, lv;
    transform(proj[base] + bk, proj[base + SE] + bh, lc, lv);
    A += lc;
    S = lse_step(lc, lv, S);
    base += 2 * SE;
  }
  int chain = b * SE + e;
  Ac[(size_t)c * NCHAIN + chain] = A;
  Bc[(size_t)c * NCHAIN + chain] = S;
}

// K3: scan over chunk summaries -> incoming state per chunk
__global__ __launch_bounds__(256) void k_scan2(const float* __restrict__ lh0,
                                               const float* __restrict__ Ac,
                                               const float* __restrict__ Bc,
                                               float* __restrict__ Hin) {
  int chain = blockIdx.x * 256 + threadIdx.x;  // 8192 = b*E + e
  float H = lh0[chain];
  for (int c = 0; c < NCHUNK; ++c) {
    Hin[(size_t)c * NCHAIN + chain] = H;
    float a = Ac[(size_t)c * NCHAIN + chain] + H;
    float bv = Bc[(size_t)c * NCHAIN + chain];
    float m = fmaxf(a, bv);
    float d = fminf(a, bv) - m;
    H = m + __logf(1.f + __expf(d));
  }
}

// K4: replay scan (recomputing lv/lc from proj) with true incoming state;
// emit h_t (bf16) and out2 slices (f32)
__global__ __launch_bounds__(256) void k_scan3(const float* __restrict__ proj,
                                               const float* __restrict__ bfv,
                                               const float* __restrict__ Hin,
                                               unsigned short* __restrict__ ht,
                                               float* __restrict__ out2) {
  int idx = blockIdx.x * 256 + threadIdx.x;
  int e = idx & (SE - 1), b = (idx >> 11) & 3, c = idx >> 13;
  const float bk = bfv[e], bh = bfv[SE + e];
  float S = Hin[(size_t)c * NCHAIN + b * SE + e];
  size_t base = ((size_t)(b * ST + c * CHUNK) * (2 * SE)) + e;
  int t = c * CHUNK;
  size_t hto = ((size_t)(b * ST + t) * SE) + e;
  for (int i = 0; i < CHUNK; ++i, ++t) {
    float lc, lv;
    transform(proj[base] + bk, proj[base + SE] + bh, lc, lv);
    S = lse_step(lc, lv, S);
    ht[hto] = f2bf(__expf(S));
    if (t >= 2 && ((t - 2) % 3) == 0) {   // t in {2,5,...,4094}
      int j = (t - 2) / 3;
      out2[((size_t)b * 1365 + j) * SE + e] = S;
    }
    base += 2 * SE;
    hto += SE;
  }
}

// ---------- launch ----------
extern "C" void kernel_launch(void* const* d_in, const int* in_sizes, int n_in,
                              void* d_out, int out_size, void* d_ws, size_t ws_size,
                              hipStream_t stream) {
  const float* x   = (const float*)d_in[0];
  const float* lh0 = (const float*)d_in[1];
  const float* wf  = (const float*)d_in[2];
  const float* bfv = (const float*)d_in[3];
  const float* wd  = (const float*)d_in[4];
  float* out1 = (float*)d_out;
  float* out2 = out1 + (size_t)SB * ST * 1024;

  char* p = (char*)d_ws;
  float* proj          = (float*)p;          p += 16384ull * 4096 * 4;  // 268 MB
  unsigned short* xhi  = (unsigned short*)p; p += 16384ull * 1024 * 2;
  unsigned short* wfh  = (unsigned short*)p; p += 4096ull * 1024 * 2;
  unsigned short* wdt  = (unsigned short*)p; p += 1024ull * 2048 * 2;
  unsigned short* ht   = (unsigned short*)p; p += 16384ull * 2048 * 2;  // 67 MB
  float* Ac            = (float*)p;          p += 64ull * 8192 * 4;
  float* Bc            = (float*)p;          p += 64ull * 8192 * 4;
  float* Hin           = (float*)p;          p += 64ull * 8192 * 4;

  // pre-passes
  hipLaunchKernelGGL(k_cast, dim3(16384), dim3(256), 0, stream, x, xhi);
  hipLaunchKernelGGL(k_transpose, dim3(128, 32), dim3(256), 0, stream, wf, wfh, 1024, 4096);
  hipLaunchKernelGGL(k_transpose, dim3(32, 64),  dim3(256), 0, stream, wd, wdt, 2048, 1024);
  // GEMM1 (bf16): proj = x @ w_f
  hipLaunchKernelGGL(k_gemm, dim3(128, 32), dim3(256), 0, stream,
                     xhi, wfh, proj, 16384, 4096, 1024);
  // 3-pass chunked log-space scan (proj read-only; scan3 recomputes transforms)
  hipLaunchKernelGGL(k_scan1, dim3(2048), dim3(256), 0, stream, proj, bfv, Ac, Bc);
  hipLaunchKernelGGL(k_scan2, dim3(32), dim3(256), 0, stream, lh0, Ac, Bc, Hin);
  hipLaunchKernelGGL(k_scan3, dim3(2048), dim3(256), 0, stream, proj, bfv, Hin, ht, out2);
  // GEMM2 (bf16): out1 = h_t @ w_down
  hipLaunchKernelGGL(k_gemm, dim3(128, 8), dim3(256), 0, stream,
                     ht, wdt, out1, 16384, 1024, 2048);
}

// Round 6
// 430.154 us; speedup vs baseline: 4.0161x; 1.0911x over previous
//
#include <hip/hip_runtime.h>
#include <cstdint>
#include <cstddef>

typedef __attribute__((ext_vector_type(4))) float f32x4;
typedef __attribute__((ext_vector_type(8))) short short8;

// ---------- bf16 helpers (bit-level, header-version independent) ----------
__device__ __forceinline__ unsigned short f2bf(float f) {
  unsigned int u = __float_as_uint(f);
  u += 0x7fffu + ((u >> 16) & 1u);            // round to nearest even
  return (unsigned short)(u >> 16);
}
__device__ __forceinline__ float bf2f(unsigned short h) {
  return __uint_as_float(((unsigned int)h) << 16);
}

__device__ __forceinline__ void gload16(const unsigned short* g, unsigned short* l) {
  __builtin_amdgcn_global_load_lds(
      (const __attribute__((address_space(1))) void*)g,
      (__attribute__((address_space(3))) void*)l, 16, 0, 0);
}

// ---------- P1: x f32 -> bf16 ----------
__global__ __launch_bounds__(256) void k_cast(const float* __restrict__ src,
                                              unsigned short* __restrict__ hi) {
  size_t i = ((size_t)blockIdx.x * 256 + threadIdx.x) * 4;
  float4 v = *(const float4*)(src + i);
  *(ushort4*)(hi + i) = make_ushort4(f2bf(v.x), f2bf(v.y), f2bf(v.z), f2bf(v.w));
}

// ---------- P2/P3: transpose f32 [R][C] -> bf16 [C][R] ----------
__global__ __launch_bounds__(256) void k_transpose(const float* __restrict__ src,
                                                   unsigned short* __restrict__ hi,
                                                   int R, int C) {
  __shared__ float tile[32][33];
  int tx = threadIdx.x & 31, ty = threadIdx.x >> 5;  // ty 0..7
  int c0 = blockIdx.x * 32, r0 = blockIdx.y * 32;
#pragma unroll
  for (int i = 0; i < 4; ++i)
    tile[ty + 8 * i][tx] = src[(size_t)(r0 + ty + 8 * i) * C + (c0 + tx)];
  __syncthreads();
#pragma unroll
  for (int i = 0; i < 4; ++i) {
    float v = tile[tx][ty + 8 * i];
    hi[(size_t)(c0 + ty + 8 * i) * R + (r0 + tx)] = f2bf(v);
  }
}

// ---------- GEMM: A[M][K] (bf16, k-contig), B[N][K] (bf16, k-contig) -> C[M][N] f32
// 256x256 tile, BK=32, 8 waves (2Mx4N), 4-buffer LDS ring, prefetch distance 3,
// counted vmcnt (never 0 in steady state) + raw s_barrier (no drain).
// Per K-step/wave: 4 global_load_lds (tile t+3), 12 ds_read_b128, 32 MFMA.
// Correctness of counted waits: each wave issues exactly 4 loads per tile in
// program order; vmcnt(8)+barrier => every wave's tile-t loads landed => tile t
// complete in LDS (m135 oldest-first rule). Barrier BEFORE stage keeps writers
// off buf[(t+3)%4]=buf[(t-1)%4] until all readers of step t-1 passed it.
// LDS layout per buffer: A[256][32] ++ B[256][32], 64B rows, k-slot XOR-swizzled
// (slot ks holds k-chunk ks ^ ((row>>1)&3)); staging pre-swizzles the GLOBAL
// k-offset per thread (linear LDS dest), fragment reads apply the same XOR ->
// 2-way (free) LDS banking. Verified layout/swizzle from the 128^2 version.
__global__ __launch_bounds__(512, 2) void k_gemm(const unsigned short* __restrict__ A,
                                                 const unsigned short* __restrict__ B,
                                                 float* __restrict__ C, int M, int N, int K) {
  __shared__ unsigned short lds[4][16384];   // 4 x 32KB = 128KB
  const int tid = threadIdx.x, wave = tid >> 6, lane = tid & 63;
  const size_t row0 = (size_t)blockIdx.x * 256;
  const size_t col0 = (size_t)blockIdx.y * 256;
  const int wr = wave >> 2, wc = wave & 3;          // 2M x 4N waves
  const int r16 = lane & 15;
  const int ksw = ((lane >> 4) ^ ((r16 >> 1) & 3)); // swizzled k-slot for fragment reads
  // fragment offsets (shorts): row*32 + ksw*8 ; B region starts at 8192 shorts
  const int abase = (wr * 128 + r16) * 32 + ksw * 8;
  const int bbase = 8192 + (wc * 64 + r16) * 32 + ksw * 8;
  // staging: thread tid covers LDS bytes [tid*16,+16) of an 8KB instr region:
  // row = inst*128 + (tid>>2), phys slot = tid&3 -> global k-chunk pre-swizzled:
  const int gks = ((tid & 3) ^ ((tid >> 3) & 3)) * 8;   // shorts
  const size_t arow = (size_t)(tid >> 2);
  const int ldsw = wave * 512;                           // per-wave slice of instr region (shorts)

  f32x4 acc[8][4];
#pragma unroll
  for (int i = 0; i < 8; ++i)
#pragma unroll
    for (int j = 0; j < 4; ++j) acc[i][j] = (f32x4){0.f, 0.f, 0.f, 0.f};

  const int nT = K >> 5;  // K/32 tiles

  // stage tile kt into buffer b: 4 global_load_lds per wave (A x2, B x2)
  auto STAGE = [&](int b, int kt) {
    int k0 = kt << 5;
#pragma unroll
    for (int inst = 0; inst < 2; ++inst) {
      gload16(A + (row0 + (size_t)inst * 128 + arow) * (size_t)K + (size_t)(k0 + gks),
              &lds[b][inst * 4096 + ldsw]);
      gload16(B + (col0 + (size_t)inst * 128 + arow) * (size_t)K + (size_t)(k0 + gks),
              &lds[b][8192 + inst * 4096 + ldsw]);
    }
  };

  STAGE(0, 0);
  STAGE(1, 1);
  STAGE(2, 2);

  for (int t = 0; t < nT; ++t) {
    // counted wait: guarantee tile t's 4 loads (per wave) have landed
    int rem = nT - 1 - t;  // tiles staged beyond t
    if (rem >= 2)      asm volatile("s_waitcnt vmcnt(8)" ::: "memory");
    else if (rem == 1) asm volatile("s_waitcnt vmcnt(4)" ::: "memory");
    else               asm volatile("s_waitcnt vmcnt(0)" ::: "memory");
    asm volatile("s_barrier" ::: "memory");   // raw barrier: NO vmcnt(0) drain
    if (t + 3 < nT) STAGE((t + 3) & 3, t + 3);

    const unsigned short* buf = lds[t & 3];
    short8 a[4], b4[4];
#pragma unroll
    for (int nb = 0; nb < 4; ++nb)
      b4[nb] = *(const short8*)&buf[bbase + nb * 512];
#pragma unroll
    for (int mb = 0; mb < 4; ++mb)
      a[mb] = *(const short8*)&buf[abase + mb * 512];
    __builtin_amdgcn_s_setprio(1);
#pragma unroll
    for (int mb = 0; mb < 4; ++mb)
#pragma unroll
      for (int nb = 0; nb < 4; ++nb)
        acc[mb][nb] = __builtin_amdgcn_mfma_f32_16x16x32_bf16(a[mb], b4[nb], acc[mb][nb], 0, 0, 0);
    __builtin_amdgcn_s_setprio(0);
#pragma unroll
    for (int mb = 0; mb < 4; ++mb)
      a[mb] = *(const short8*)&buf[abase + (4 + mb) * 512];
    __builtin_amdgcn_s_setprio(1);
#pragma unroll
    for (int mb = 0; mb < 4; ++mb)
#pragma unroll
      for (int nb = 0; nb < 4; ++nb)
        acc[4 + mb][nb] = __builtin_amdgcn_mfma_f32_16x16x32_bf16(a[mb], b4[nb], acc[4 + mb][nb], 0, 0, 0);
    __builtin_amdgcn_s_setprio(0);
  }

  // C/D layout (HW-verified): col = lane&15, row = (lane>>4)*4 + reg
#pragma unroll
  for (int mb = 0; mb < 8; ++mb)
#pragma unroll
    for (int nb = 0; nb < 4; ++nb) {
      size_t row = row0 + wr * 128 + mb * 16 + (lane >> 4) * 4;
      size_t col = col0 + wc * 64 + nb * 16 + r16;
      float* cp = C + row * (size_t)N + col;
#pragma unroll
      for (int r = 0; r < 4; ++r) cp[(size_t)r * N] = acc[mb][nb][r];
    }
}

// ---------- scan constants ----------
#define SB 4
#define ST 4096
#define SE 2048
#define CHUNK 64
#define NCHUNK 64
#define NCHAIN (SB * SE)  // 8192

// transforms via native v_exp_f32/v_log_f32 (__expf/__logf), ~1e-7 abs error in
// log-space (irrelevant vs 0.134 budget).
__device__ __forceinline__ void transform(float k, float hx, float& lc, float& lv) {
  float u = __expf(-fabsf(k));
  float sp = fmaxf(k, 0.f) + __logf(1.f + u);   // softplus(k)
  lc = -sp;                                     // log(1 - sigmoid(k))
  float eh = __expf(fminf(hx, 0.f));            // exp(hx) for hx<0 (clamped: no overflow)
  float arg = (hx >= 0.f) ? (hx + 0.5f) : (1.f + eh);
  float vl = __logf(arg);
  float lg = (hx >= 0.f) ? vl : (hx - vl);      // log g(hx)
  lv = lg + k + lc;                             // log g + log sigmoid(k)
}
__device__ __forceinline__ float lse_step(float lc, float lv, float S) {
  float a1 = lc + S;
  float m = fmaxf(a1, lv);
  float d = fminf(a1, lv) - m;                  // <= 0 (or -inf)
  return m + __logf(1.f + __expf(d));
}

// K2: transforms + chunk-local scan (from -inf) -> chunk summaries ONLY.
__global__ __launch_bounds__(256) void k_scan1(const float* __restrict__ proj,
                                               const float* __restrict__ bfv,
                                               float* __restrict__ Ac,
                                               float* __restrict__ Bc) {
  int idx = blockIdx.x * 256 + threadIdx.x;  // (c, b, e) with e fastest
  int e = idx & (SE - 1), b = (idx >> 11) & 3, c = idx >> 13;
  const float bk = bfv[e], bh = bfv[SE + e];
  float A = 0.f, S = -INFINITY;
  size_t base = ((size_t)(b * ST + c * CHUNK) * (2 * SE)) + e;
  for (int i = 0; i < CHUNK; ++i) {
    float lc, lv;
    transform(proj[base] + bk, proj[base + SE] + bh, lc, lv);
    A += lc;
    S = lse_step(lc, lv, S);
    base += 2 * SE;
  }
  int chain = b * SE + e;
  Ac[(size_t)c * NCHAIN + chain] = A;
  Bc[(size_t)c * NCHAIN + chain] = S;
}

// K3: scan over chunk summaries -> incoming state per chunk
__global__ __launch_bounds__(256) void k_scan2(const float* __restrict__ lh0,
                                               const float* __restrict__ Ac,
                                               const float* __restrict__ Bc,
                                               float* __restrict__ Hin) {
  int chain = blockIdx.x * 256 + threadIdx.x;  // 8192 = b*E + e
  float H = lh0[chain];
  for (int c = 0; c < NCHUNK; ++c) {
    Hin[(size_t)c * NCHAIN + chain] = H;
    float a = Ac[(size_t)c * NCHAIN + chain] + H;
    float bv = Bc[(size_t)c * NCHAIN + chain];
    float m = fmaxf(a, bv);
    float d = fminf(a, bv) - m;
    H = m + __logf(1.f + __expf(d));
  }
}

// K4: replay scan (recomputing lv/lc from proj) with true incoming state;
// emit h_t (bf16) and out2 slices (f32)
__global__ __launch_bounds__(256) void k_scan3(const float* __restrict__ proj,
                                               const float* __restrict__ bfv,
                                               const float* __restrict__ Hin,
                                               unsigned short* __restrict__ ht,
                                               float* __restrict__ out2) {
  int idx = blockIdx.x * 256 + threadIdx.x;
  int e = idx & (SE - 1), b = (idx >> 11) & 3, c = idx >> 13;
  const float bk = bfv[e], bh = bfv[SE + e];
  float S = Hin[(size_t)c * NCHAIN + b * SE + e];
  size_t base = ((size_t)(b * ST + c * CHUNK) * (2 * SE)) + e;
  int t = c * CHUNK;
  size_t hto = ((size_t)(b * ST + t) * SE) + e;
  for (int i = 0; i < CHUNK; ++i, ++t) {
    float lc, lv;
    transform(proj[base] + bk, proj[base + SE] + bh, lc, lv);
    S = lse_step(lc, lv, S);
    ht[hto] = f2bf(__expf(S));
    if (t >= 2 && ((t - 2) % 3) == 0) {   // t in {2,5,...,4094}
      int j = (t - 2) / 3;
      out2[((size_t)b * 1365 + j) * SE + e] = S;
    }
    base += 2 * SE;
    hto += SE;
  }
}

// ---------- launch ----------
extern "C" void kernel_launch(void* const* d_in, const int* in_sizes, int n_in,
                              void* d_out, int out_size, void* d_ws, size_t ws_size,
                              hipStream_t stream) {
  const float* x   = (const float*)d_in[0];
  const float* lh0 = (const float*)d_in[1];
  const float* wf  = (const float*)d_in[2];
  const float* bfv = (const float*)d_in[3];
  const float* wd  = (const float*)d_in[4];
  float* out1 = (float*)d_out;
  float* out2 = out1 + (size_t)SB * ST * 1024;

  char* p = (char*)d_ws;
  float* proj          = (float*)p;          p += 16384ull * 4096 * 4;  // 268 MB
  unsigned short* xhi  = (unsigned short*)p; p += 16384ull * 1024 * 2;
  unsigned short* wfh  = (unsigned short*)p; p += 4096ull * 1024 * 2;
  unsigned short* wdt  = (unsigned short*)p; p += 1024ull * 2048 * 2;
  unsigned short* ht   = (unsigned short*)p; p += 16384ull * 2048 * 2;  // 67 MB
  float* Ac            = (float*)p;          p += 64ull * 8192 * 4;
  float* Bc            = (float*)p;          p += 64ull * 8192 * 4;
  float* Hin           = (float*)p;          p += 64ull * 8192 * 4;

  // pre-passes
  hipLaunchKernelGGL(k_cast, dim3(16384), dim3(256), 0, stream, x, xhi);
  hipLaunchKernelGGL(k_transpose, dim3(128, 32), dim3(256), 0, stream, wf, wfh, 1024, 4096);
  hipLaunchKernelGGL(k_transpose, dim3(32, 64),  dim3(256), 0, stream, wd, wdt, 2048, 1024);
  // GEMM1 (bf16): proj = x @ w_f   (256^2 tiles)
  hipLaunchKernelGGL(k_gemm, dim3(64, 16), dim3(512), 0, stream,
                     xhi, wfh, proj, 16384, 4096, 1024);
  // 3-pass chunked log-space scan (proj read-only; scan3 recomputes transforms)
  hipLaunchKernelGGL(k_scan1, dim3(2048), dim3(256), 0, stream, proj, bfv, Ac, Bc);
  hipLaunchKernelGGL(k_scan2, dim3(32), dim3(256), 0, stream, lh0, Ac, Bc, Hin);
  hipLaunchKernelGGL(k_scan3, dim3(2048), dim3(256), 0, stream, proj, bfv, Hin, ht, out2);
  // GEMM2 (bf16): out1 = h_t @ w_down   (256^2 tiles)
  hipLaunchKernelGGL(k_gemm, dim3(64, 4), dim3(512), 0, stream,
                     ht, wdt, out1, 16384, 1024, 2048);
}

// Round 7
// 409.357 us; speedup vs baseline: 4.2201x; 1.0508x over previous
//
#include <hip/hip_runtime.h>
#include <cstdint>
#include <cstddef>

typedef __attribute__((ext_vector_type(4))) float f32x4;
typedef __attribute__((ext_vector_type(8))) short short8;

// ---------- bf16 helpers (bit-level, header-version independent) ----------
__device__ __forceinline__ unsigned short f2bf(float f) {
  unsigned int u = __float_as_uint(f);
  u += 0x7fffu + ((u >> 16) & 1u);            // round to nearest even
  return (unsigned short)(u >> 16);
}
__device__ __forceinline__ float bf2f(unsigned short h) {
  return __uint_as_float(((unsigned int)h) << 16);
}

__device__ __forceinline__ void gload16(const unsigned short* g, unsigned short* l) {
  __builtin_amdgcn_global_load_lds(
      (const __attribute__((address_space(1))) void*)g,
      (__attribute__((address_space(3))) void*)l, 16, 0, 0);
}

// ---------- P1: x f32 -> bf16 ----------
__global__ __launch_bounds__(256) void k_cast(const float* __restrict__ src,
                                              unsigned short* __restrict__ hi) {
  size_t i = ((size_t)blockIdx.x * 256 + threadIdx.x) * 4;
  float4 v = *(const float4*)(src + i);
  *(ushort4*)(hi + i) = make_ushort4(f2bf(v.x), f2bf(v.y), f2bf(v.z), f2bf(v.w));
}

// ---------- P2/P3: transpose f32 [R][C] -> bf16 [C][R] ----------
__global__ __launch_bounds__(256) void k_transpose(const float* __restrict__ src,
                                                   unsigned short* __restrict__ hi,
                                                   int R, int C) {
  __shared__ float tile[32][33];
  int tx = threadIdx.x & 31, ty = threadIdx.x >> 5;  // ty 0..7
  int c0 = blockIdx.x * 32, r0 = blockIdx.y * 32;
#pragma unroll
  for (int i = 0; i < 4; ++i)
    tile[ty + 8 * i][tx] = src[(size_t)(r0 + ty + 8 * i) * C + (c0 + tx)];
  __syncthreads();
#pragma unroll
  for (int i = 0; i < 4; ++i) {
    float v = tile[tx][ty + 8 * i];
    hi[(size_t)(c0 + ty + 8 * i) * R + (r0 + tx)] = f2bf(v);
  }
}

// ---------- GEMM: A[M][K] (bf16, k-contig), B[N][K] (bf16, k-contig) -> C[M][N] f32
// 8-phase 256x256 template (T2+T3+T4+T5): BK=64, 8 waves (2M x 4N, wave-tile
// 128x64), LDS = 2 buffers x (A[256][64] + B[256][64]) = 128 KB, 1 block/CU.
// Per K-tile: 4 quadrant phases (h,v) = (0,0),(0,1),(1,1),(1,0); per phase:
// {ds_read subtile for THIS phase | stage 2 regions of tile u+1 into the OTHER
// buffer | setprio(1) 16 MFMA setprio(0)}; one raw s_barrier per phase start.
// Counted vmcnt, never drained mid-loop except the final tile:
//   piece issue order per tile u (into buf (u+1)&1): B01@ph1, B23@ph2, A02@ph3,
//   A13@ph4 (regions r = 64-row slabs; A02={A_r0,A_r2} feeds both wr halves'
//   A0-half, A13 feeds A1-half).
//   ph1(u) reads A0(u),B0(u): need A02(u) [staged ph3(u-1)] + all B(u) [older]
//     -> in-flight <= {A02(u),A13(u)}: wait vmcnt(2) leaves A13 only.
//   ph3(u) reads A1(u): need A13(u) [staged ph4(u-1)]
//     -> in-flight {A13(u),B01(u+1),B23(u+1)}: wait vmcnt(4) (vmcnt(0) last tile).
//   Loads complete oldest-first for counting (m135), so older pieces are covered.
// Writer buffer != reader buffer in every phase; region writes are separated
// from that region's last reads by >=2 barriers -> race-free by construction.
// LDS swizzle: row of 64 k = 8 slots of 8 shorts; phys slot p at row r holds
// global k-chunk p ^ (r&7). Staged with linear LDS dest + pre-swizzled global
// k (both-sides rule); fragment reads XOR the same -> 2-way banking (free).
// A/B fragments use the identical (lane -> k-chunk) convention -> contraction
// correct independent of HW k-labeling (same argument as verified 128^2 kernel).
__global__ __launch_bounds__(512, 2) void k_gemm(const unsigned short* __restrict__ A,
                                                 const unsigned short* __restrict__ B,
                                                 float* __restrict__ C, int M, int N, int K) {
  __shared__ unsigned short lds[65536];      // 2 x 32768 shorts = 128 KB
  const int tid = threadIdx.x, wave = tid >> 6, lane = tid & 63;
  const size_t row0 = (size_t)blockIdx.x * 256;
  const size_t col0 = (size_t)blockIdx.y * 256;
  const int wr = wave >> 2, wc = wave & 3;   // 2M x 4N waves
  const int r16 = lane & 15;
  const int lg = lane >> 4;                  // 0..3
  // staging: wave covers 512 shorts of each 4096-short (64-row) region;
  // lane's LDS slot = lane&7, row-in-region = wave*8 + (lane>>3);
  // global k-chunk pre-swizzled to land the XOR pattern with a LINEAR dest.
  const int schunk = (lane & 7) ^ ((lane >> 3) & 7);
  const int srow = wave * 8 + (lane >> 3);

  f32x4 acc[8][4];
#pragma unroll
  for (int i = 0; i < 8; ++i)
#pragma unroll
    for (int j = 0; j < 4; ++j) acc[i][j] = (f32x4){0.f, 0.f, 0.f, 0.f};

  // stage one 8KB region (arr 0=A,1=B; reg 0..3) of K-tile kt into buffer b
  auto SREG = [&](int b, int arr, int reg, int kt) {
    const unsigned short* src = arr ? B : A;
    size_t grow = (arr ? col0 : row0) + (size_t)(reg * 64 + srow);
    gload16(src + grow * (size_t)K + (size_t)(kt * 64 + schunk * 8),
            &lds[(b << 15) + arr * 16384 + reg * 4096 + wave * 512]);
  };
  // fragment offsets (shorts): row*64 + swizzled-slot*8
  auto AOFF = [&](int h, int mb, int s) -> int {
    int r = wr * 128 + h * 64 + mb * 16 + r16;
    return r * 64 + (((s * 4 + lg) ^ (r16 & 7)) * 8);
  };
  auto BOFF = [&](int v, int nb, int s) -> int {
    int r = wc * 64 + v * 32 + nb * 16 + r16;
    return 16384 + r * 64 + (((s * 4 + lg) ^ (r16 & 7)) * 8);
  };

  const unsigned short* buf;
  short8 a[4][2], b0[2][2], b1[2][2];
  auto LDA = [&](int h) {
#pragma unroll
    for (int mb = 0; mb < 4; ++mb)
#pragma unroll
      for (int s = 0; s < 2; ++s)
        a[mb][s] = *(const short8*)&buf[AOFF(h, mb, s)];
  };
  auto LDB = [&](short8 (&bb)[2][2], int v) {
#pragma unroll
    for (int nb = 0; nb < 2; ++nb)
#pragma unroll
      for (int s = 0; s < 2; ++s)
        bb[nb][s] = *(const short8*)&buf[BOFF(v, nb, s)];
  };
  auto MMA = [&](int h, int v, short8 (&bb)[2][2]) {
    __builtin_amdgcn_s_setprio(1);
#pragma unroll
    for (int s = 0; s < 2; ++s)
#pragma unroll
      for (int mb = 0; mb < 4; ++mb)
#pragma unroll
        for (int nb = 0; nb < 2; ++nb)
          acc[h * 4 + mb][v * 2 + nb] = __builtin_amdgcn_mfma_f32_16x16x32_bf16(
              a[mb][s], bb[nb][s], acc[h * 4 + mb][v * 2 + nb], 0, 0, 0);
    __builtin_amdgcn_s_setprio(0);
  };

  // prologue: stage tile 0 fully, in piece order B01,B23,A02,A13
  SREG(0, 1, 0, 0); SREG(0, 1, 1, 0);
  SREG(0, 1, 2, 0); SREG(0, 1, 3, 0);
  SREG(0, 0, 0, 0); SREG(0, 0, 2, 0);
  SREG(0, 0, 1, 0); SREG(0, 0, 3, 0);

  const int nT = K >> 6;
  for (int u = 0; u < nT; ++u) {
    buf = &lds[(u & 1) << 15];
    const int ob = (u & 1) ^ 1;
    const int kn = u + 1;
    const bool pf = (kn < nT);
    // ---- phase 1: quadrant (0,0) ----
    asm volatile("s_waitcnt vmcnt(2)" ::: "memory");
    asm volatile("s_barrier" ::: "memory");
    LDA(0); LDB(b0, 0);
    if (pf) { SREG(ob, 1, 0, kn); SREG(ob, 1, 1, kn); }
    MMA(0, 0, b0);
    // ---- phase 2: quadrant (0,1) ----
    asm volatile("s_barrier" ::: "memory");
    LDB(b1, 1);
    if (pf) { SREG(ob, 1, 2, kn); SREG(ob, 1, 3, kn); }
    MMA(0, 1, b1);
    // ---- phase 3: quadrant (1,1) ----
    if (pf) asm volatile("s_waitcnt vmcnt(4)" ::: "memory");
    else    asm volatile("s_waitcnt vmcnt(0)" ::: "memory");
    asm volatile("s_barrier" ::: "memory");
    LDA(1);
    if (pf) { SREG(ob, 0, 0, kn); SREG(ob, 0, 2, kn); }
    MMA(1, 1, b1);
    // ---- phase 4: quadrant (1,0) ----
    asm volatile("s_barrier" ::: "memory");
    if (pf) { SREG(ob, 0, 1, kn); SREG(ob, 0, 3, kn); }
    MMA(1, 0, b0);
  }

  // C/D layout (HW-verified): col = lane&15, row = (lane>>4)*4 + reg
#pragma unroll
  for (int m = 0; m < 8; ++m)
#pragma unroll
    for (int n = 0; n < 4; ++n) {
      size_t row = row0 + wr * 128 + m * 16 + (lane >> 4) * 4;
      size_t col = col0 + wc * 64 + n * 16 + r16;
      float* cp = C + row * (size_t)N + col;
#pragma unroll
      for (int r = 0; r < 4; ++r) cp[(size_t)r * N] = acc[m][n][r];
    }
}

// ---------- scan constants ----------
#define SB 4
#define ST 4096
#define SE 2048
#define CHUNK 64
#define NCHUNK 64
#define NCHAIN (SB * SE)  // 8192

// transforms via native v_exp_f32/v_log_f32 (__expf/__logf), ~1e-7 abs error in
// log-space (irrelevant vs 0.134 budget).
__device__ __forceinline__ void transform(float k, float hx, float& lc, float& lv) {
  float u = __expf(-fabsf(k));
  float sp = fmaxf(k, 0.f) + __logf(1.f + u);   // softplus(k)
  lc = -sp;                                     // log(1 - sigmoid(k))
  float eh = __expf(fminf(hx, 0.f));            // exp(hx) for hx<0 (clamped: no overflow)
  float arg = (hx >= 0.f) ? (hx + 0.5f) : (1.f + eh);
  float vl = __logf(arg);
  float lg = (hx >= 0.f) ? vl : (hx - vl);      // log g(hx)
  lv = lg + k + lc;                             // log g + log sigmoid(k)
}
__device__ __forceinline__ float lse_step(float lc, float lv, float S) {
  float a1 = lc + S;
  float m = fmaxf(a1, lv);
  float d = fminf(a1, lv) - m;                  // <= 0 (or -inf)
  return m + __logf(1.f + __expf(d));
}

// K2: transforms + chunk-local scan (from -inf) -> chunk summaries ONLY.
__global__ __launch_bounds__(256) void k_scan1(const float* __restrict__ proj,
                                               const float* __restrict__ bfv,
                                               float* __restrict__ Ac,
                                               float* __restrict__ Bc) {
  int idx = blockIdx.x * 256 + threadIdx.x;  // (c, b, e) with e fastest
  int e = idx & (SE - 1), b = (idx >> 11) & 3, c = idx >> 13;
  const float bk = bfv[e], bh = bfv[SE + e];
  float A = 0.f, S = -INFINITY;
  size_t base = ((size_t)(b * ST + c * CHUNK) * (2 * SE)) + e;
  for (int i = 0; i < CHUNK; ++i) {
    float lc, lv;
    transform(proj[base] + bk, proj[base + SE] + bh, lc, lv);
    A += lc;
    S = lse_step(lc, lv, S);
    base += 2 * SE;
  }
  int chain = b * SE + e;
  Ac[(size_t)c * NCHAIN + chain] = A;
  Bc[(size_t)c * NCHAIN + chain] = S;
}

// K3: scan over chunk summaries -> incoming state per chunk
__global__ __launch_bounds__(256) void k_scan2(const float* __restrict__ lh0,
                                               const float* __restrict__ Ac,
                                               const float* __restrict__ Bc,
                                               float* __restrict__ Hin) {
  int chain = blockIdx.x * 256 + threadIdx.x;  // 8192 = b*E + e
  float H = lh0[chain];
  for (int c = 0; c < NCHUNK; ++c) {
    Hin[(size_t)c * NCHAIN + chain] = H;
    float a = Ac[(size_t)c * NCHAIN + chain] + H;
    float bv = Bc[(size_t)c * NCHAIN + chain];
    float m = fmaxf(a, bv);
    float d = fminf(a, bv) - m;
    H = m + __logf(1.f + __expf(d));
  }
}

// K4: replay scan (recomputing lv/lc from proj) with true incoming state;
// emit h_t (bf16) and out2 slices (f32)
__global__ __launch_bounds__(256) void k_scan3(const float* __restrict__ proj,
                                               const float* __restrict__ bfv,
                                               const float* __restrict__ Hin,
                                               unsigned short* __restrict__ ht,
                                               float* __restrict__ out2) {
  int idx = blockIdx.x * 256 + threadIdx.x;
  int e = idx & (SE - 1), b = (idx >> 11) & 3, c = idx >> 13;
  const float bk = bfv[e], bh = bfv[SE + e];
  float S = Hin[(size_t)c * NCHAIN + b * SE + e];
  size_t base = ((size_t)(b * ST + c * CHUNK) * (2 * SE)) + e;
  int t = c * CHUNK;
  size_t hto = ((size_t)(b * ST + t) * SE) + e;
  for (int i = 0; i < CHUNK; ++i, ++t) {
    float lc, lv;
    transform(proj[base] + bk, proj[base + SE] + bh, lc, lv);
    S = lse_step(lc, lv, S);
    ht[hto] = f2bf(__expf(S));
    if (t >= 2 && ((t - 2) % 3) == 0) {   // t in {2,5,...,4094}
      int j = (t - 2) / 3;
      out2[((size_t)b * 1365 + j) * SE + e] = S;
    }
    base += 2 * SE;
    hto += SE;
  }
}

// ---------- launch ----------
extern "C" void kernel_launch(void* const* d_in, const int* in_sizes, int n_in,
                              void* d_out, int out_size, void* d_ws, size_t ws_size,
                              hipStream_t stream) {
  const float* x   = (const float*)d_in[0];
  const float* lh0 = (const float*)d_in[1];
  const float* wf  = (const float*)d_in[2];
  const float* bfv = (const float*)d_in[3];
  const float* wd  = (const float*)d_in[4];
  float* out1 = (float*)d_out;
  float* out2 = out1 + (size_t)SB * ST * 1024;

  char* p = (char*)d_ws;
  float* proj          = (float*)p;          p += 16384ull * 4096 * 4;  // 268 MB
  unsigned short* xhi  = (unsigned short*)p; p += 16384ull * 1024 * 2;
  unsigned short* wfh  = (unsigned short*)p; p += 4096ull * 1024 * 2;
  unsigned short* wdt  = (unsigned short*)p; p += 1024ull * 2048 * 2;
  unsigned short* ht   = (unsigned short*)p; p += 16384ull * 2048 * 2;  // 67 MB
  float* Ac            = (float*)p;          p += 64ull * 8192 * 4;
  float* Bc            = (float*)p;          p += 64ull * 8192 * 4;
  float* Hin           = (float*)p;          p += 64ull * 8192 * 4;

  // pre-passes
  hipLaunchKernelGGL(k_cast, dim3(16384), dim3(256), 0, stream, x, xhi);
  hipLaunchKernelGGL(k_transpose, dim3(128, 32), dim3(256), 0, stream, wf, wfh, 1024, 4096);
  hipLaunchKernelGGL(k_transpose, dim3(32, 64),  dim3(256), 0, stream, wd, wdt, 2048, 1024);
  // GEMM1 (bf16): proj = x @ w_f   (256^2 8-phase)
  hipLaunchKernelGGL(k_gemm, dim3(64, 16), dim3(512), 0, stream,
                     xhi, wfh, proj, 16384, 4096, 1024);
  // 3-pass chunked log-space scan (proj read-only; scan3 recomputes transforms)
  hipLaunchKernelGGL(k_scan1, dim3(2048), dim3(256), 0, stream, proj, bfv, Ac, Bc);
  hipLaunchKernelGGL(k_scan2, dim3(32), dim3(256), 0, stream, lh0, Ac, Bc, Hin);
  hipLaunchKernelGGL(k_scan3, dim3(2048), dim3(256), 0, stream, proj, bfv, Hin, ht, out2);
  // GEMM2 (bf16): out1 = h_t @ w_down   (256^2 8-phase)
  hipLaunchKernelGGL(k_gemm, dim3(64, 4), dim3(512), 0, stream,
                     ht, wdt, out1, 16384, 1024, 2048);
}

// Round 8
// 386.913 us; speedup vs baseline: 4.4649x; 1.0580x over previous
//
#include <hip/hip_runtime.h>
#include <cstdint>
#include <cstddef>

typedef __attribute__((ext_vector_type(4))) float f32x4;
typedef __attribute__((ext_vector_type(8))) short short8;

// ---------- bf16 helpers (bit-level, header-version independent) ----------
__device__ __forceinline__ unsigned short f2bf(float f) {
  unsigned int u = __float_as_uint(f);
  u += 0x7fffu + ((u >> 16) & 1u);            // round to nearest even
  return (unsigned short)(u >> 16);
}
__device__ __forceinline__ float bf2f(unsigned short h) {
  return __uint_as_float(((unsigned int)h) << 16);
}

__device__ __forceinline__ void gload16(const unsigned short* g, unsigned short* l) {
  __builtin_amdgcn_global_load_lds(
      (const __attribute__((address_space(1))) void*)g,
      (__attribute__((address_space(3))) void*)l, 16, 0, 0);
}

// ---------- P1: x f32 -> bf16 ----------
__global__ __launch_bounds__(256) void k_cast(const float* __restrict__ src,
                                              unsigned short* __restrict__ hi) {
  size_t i = ((size_t)blockIdx.x * 256 + threadIdx.x) * 4;
  float4 v = *(const float4*)(src + i);
  *(ushort4*)(hi + i) = make_ushort4(f2bf(v.x), f2bf(v.y), f2bf(v.z), f2bf(v.w));
}

// ---------- P2/P3: transpose f32 [R][C] -> bf16 [C][R] ----------
__global__ __launch_bounds__(256) void k_transpose(const float* __restrict__ src,
                                                   unsigned short* __restrict__ hi,
                                                   int R, int C) {
  __shared__ float tile[32][33];
  int tx = threadIdx.x & 31, ty = threadIdx.x >> 5;  // ty 0..7
  int c0 = blockIdx.x * 32, r0 = blockIdx.y * 32;
#pragma unroll
  for (int i = 0; i < 4; ++i)
    tile[ty + 8 * i][tx] = src[(size_t)(r0 + ty + 8 * i) * C + (c0 + tx)];
  __syncthreads();
#pragma unroll
  for (int i = 0; i < 4; ++i) {
    float v = tile[tx][ty + 8 * i];
    hi[(size_t)(c0 + ty + 8 * i) * R + (r0 + tx)] = f2bf(v);
  }
}

// ---------- GEMM: A[M][K] (bf16, k-contig), B[N][K] (bf16, k-contig) -> C[M][N]
// 256x256 tile, BK=32, 8 waves (2M x 4N, wave-tile 128x64), 4-buffer LDS ring
// (4 x 32KB = 128KB), prefetch distance 3 K-tiles, fine phase interleave.
// Per K-tile: ONE counted vmcnt + ONE raw s_barrier, then two half-phases:
//   halfA: ds_read B0-3 + A0-3 | stage 2 regions of tile u+3 | 16 MFMA (prio1)
//   halfB: ds_read A4-7        | stage 2 regions of tile u+3 | 16 MFMA (prio1)
// Pipeline correctness:
//  - per-wave issue order is strictly tile-ordered (4 gloads/tile); tile u's
//    loads issued 3 tiles (~6 compute half-phases, ~1800cyc) before use ->
//    vmcnt(8) (leaves tiles u+1,u+2 in flight) is a no-op in steady state
//    (m135 oldest-first counting). Tail: rem==1 -> vmcnt(4), rem==0 -> vmcnt(0).
//  - wait BEFORE barrier: each wave certifies its own tile-u loads, barrier
//    makes that collective -> buffer u&3 fully populated for all waves.
//  - writes (tile u+3 -> buf (u+3)&3=(u-1)&3) start only after ph(u)'s barrier,
//    i.e. after ALL waves finished reading tile u-1 (their reads complete
//    before their MFMAs, which precede barrier arrival) -> race-free.
// LDS swizzle (verified R5, conflicts=0): row of 32 k = 4 slots of 8 shorts;
// phys slot p at row r holds global k-chunk p ^ ((r>>1)&3). Staged with linear
// LDS dest + pre-swizzled global k; fragment reads XOR the same -> lane group
// lg reads global chunk lg for BOTH A and B (contraction convention safe).
template<bool BF16OUT>
__global__ __launch_bounds__(512, 2) void k_gemm(const unsigned short* __restrict__ A,
                                                 const unsigned short* __restrict__ B,
                                                 void* __restrict__ Cv, int M, int N, int K) {
  __shared__ unsigned short lds[65536];      // 4 bufs x 16384 shorts = 128 KB
  const int tid = threadIdx.x, wave = tid >> 6, lane = tid & 63;
  const size_t row0 = (size_t)blockIdx.x * 256;
  const size_t col0 = (size_t)blockIdx.y * 256;
  const int wr = wave >> 2, wc = wave & 3;   // 2M x 4N waves
  const int r16 = lane & 15;
  const int ksw = (lane >> 4) ^ ((r16 >> 1) & 3);       // swizzled k-slot (0..3)
  const int aoff = (wr * 128 + r16) * 32 + ksw * 8;     // A region: shorts 0..8191
  const int boff = 8192 + (wc * 64 + r16) * 32 + ksw * 8;
  const int gchunk = (tid & 3) ^ ((tid >> 3) & 3);      // pre-swizzled global k-chunk

  f32x4 acc[8][4];
#pragma unroll
  for (int i = 0; i < 8; ++i)
#pragma unroll
    for (int j = 0; j < 4; ++j) acc[i][j] = (f32x4){0.f, 0.f, 0.f, 0.f};

  // stage one 8KB region (arr 0=A,1=B; inst 0=rows 0-127,1=rows 128-255) of
  // K-tile kt into ring buffer b. Thread: row inst*128+(tid>>2), 16B at slot tid&3.
  auto SREG = [&](int b, int arr, int inst, int kt) {
    const unsigned short* src = arr ? B : A;
    size_t grow = (arr ? col0 : row0) + (size_t)(inst * 128 + (tid >> 2));
    gload16(src + grow * (size_t)K + (size_t)(kt * 32 + gchunk * 8),
            &lds[(b << 14) + arr * 8192 + inst * 4096 + wave * 512]);
  };

  // prologue: stage tiles 0,1,2 into bufs 0,1,2
#pragma unroll
  for (int t = 0; t < 3; ++t) {
    SREG(t, 0, 0, t); SREG(t, 0, 1, t);
    SREG(t, 1, 0, t); SREG(t, 1, 1, t);
  }

  const int nT = K >> 5;
  for (int u = 0; u < nT; ++u) {
    const unsigned short* buf = &lds[(u & 3) << 14];
    const int sb = (u + 3) & 3;
    const bool pf = (u + 3 < nT);
    const int rem = nT - 1 - u;
    if (rem >= 2)      asm volatile("s_waitcnt vmcnt(8)" ::: "memory");
    else if (rem == 1) asm volatile("s_waitcnt vmcnt(4)" ::: "memory");
    else               asm volatile("s_waitcnt vmcnt(0)" ::: "memory");
    asm volatile("s_barrier" ::: "memory");
    short8 a4[4], b4[4];
#pragma unroll
    for (int nb = 0; nb < 4; ++nb)
      b4[nb] = *(const short8*)&buf[boff + nb * 512];
#pragma unroll
    for (int mb = 0; mb < 4; ++mb)
      a4[mb] = *(const short8*)&buf[aoff + mb * 512];
    if (pf) { SREG(sb, 0, 0, u + 3); SREG(sb, 1, 0, u + 3); }
    __builtin_amdgcn_s_setprio(1);
#pragma unroll
    for (int mb = 0; mb < 4; ++mb)
#pragma unroll
      for (int nb = 0; nb < 4; ++nb)
        acc[mb][nb] = __builtin_amdgcn_mfma_f32_16x16x32_bf16(a4[mb], b4[nb], acc[mb][nb], 0, 0, 0);
    __builtin_amdgcn_s_setprio(0);
#pragma unroll
    for (int mb = 0; mb < 4; ++mb)
      a4[mb] = *(const short8*)&buf[aoff + (4 + mb) * 512];
    if (pf) { SREG(sb, 0, 1, u + 3); SREG(sb, 1, 1, u + 3); }
    __builtin_amdgcn_s_setprio(1);
#pragma unroll
    for (int mb = 0; mb < 4; ++mb)
#pragma unroll
      for (int nb = 0; nb < 4; ++nb)
        acc[4 + mb][nb] = __builtin_amdgcn_mfma_f32_16x16x32_bf16(a4[mb], b4[nb], acc[4 + mb][nb], 0, 0, 0);
    __builtin_amdgcn_s_setprio(0);
  }

  // C/D layout (HW-verified): col = lane&15, row = (lane>>4)*4 + reg
#pragma unroll
  for (int m = 0; m < 8; ++m)
#pragma unroll
    for (int n = 0; n < 4; ++n) {
      size_t row = row0 + wr * 128 + m * 16 + (lane >> 4) * 4;
      size_t col = col0 + wc * 64 + n * 16 + r16;
      if (BF16OUT) {
        unsigned short* C = (unsigned short*)Cv;
#pragma unroll
        for (int r = 0; r < 4; ++r) C[(row + r) * (size_t)N + col] = f2bf(acc[m][n][r]);
      } else {
        float* C = (float*)Cv;
#pragma unroll
        for (int r = 0; r < 4; ++r) C[(row + r) * (size_t)N + col] = acc[m][n][r];
      }
    }
}

// ---------- scan constants ----------
#define SB 4
#define ST 4096
#define SE 2048
#define CHUNK 64
#define NCHUNK 64
#define NCHAIN (SB * SE)  // 8192

// transforms via native v_exp_f32/v_log_f32 (__expf/__logf), ~1e-7 abs error in
// log-space (irrelevant vs 0.134 budget). proj is bf16 now (adds ~0.01-0.03
// window-bounded log-space error; budget analysis in round notes).
__device__ __forceinline__ void transform(float k, float hx, float& lc, float& lv) {
  float u = __expf(-fabsf(k));
  float sp = fmaxf(k, 0.f) + __logf(1.f + u);   // softplus(k)
  lc = -sp;                                     // log(1 - sigmoid(k))
  float eh = __expf(fminf(hx, 0.f));            // exp(hx) for hx<0 (clamped: no overflow)
  float arg = (hx >= 0.f) ? (hx + 0.5f) : (1.f + eh);
  float vl = __logf(arg);
  float lg = (hx >= 0.f) ? vl : (hx - vl);      // log g(hx)
  lv = lg + k + lc;                             // log g + log sigmoid(k)
}
__device__ __forceinline__ float lse_step(float lc, float lv, float S) {
  float a1 = lc + S;
  float m = fmaxf(a1, lv);
  float d = fminf(a1, lv) - m;                  // <= 0 (or -inf)
  return m + __logf(1.f + __expf(d));
}

// K2: transforms + chunk-local scan (from -inf) -> chunk summaries ONLY.
__global__ __launch_bounds__(256) void k_scan1(const unsigned short* __restrict__ proj,
                                               const float* __restrict__ bfv,
                                               float* __restrict__ Ac,
                                               float* __restrict__ Bc) {
  int idx = blockIdx.x * 256 + threadIdx.x;  // (c, b, e) with e fastest
  int e = idx & (SE - 1), b = (idx >> 11) & 3, c = idx >> 13;
  const float bk = bfv[e], bh = bfv[SE + e];
  float A = 0.f, S = -INFINITY;
  size_t base = ((size_t)(b * ST + c * CHUNK) * (2 * SE)) + e;
  for (int i = 0; i < CHUNK; ++i) {
    float lc, lv;
    transform(bf2f(proj[base]) + bk, bf2f(proj[base + SE]) + bh, lc, lv);
    A += lc;
    S = lse_step(lc, lv, S);
    base += 2 * SE;
  }
  int chain = b * SE + e;
  Ac[(size_t)c * NCHAIN + chain] = A;
  Bc[(size_t)c * NCHAIN + chain] = S;
}

// K3: scan over chunk summaries -> incoming state per chunk
__global__ __launch_bounds__(256) void k_scan2(const float* __restrict__ lh0,
                                               const float* __restrict__ Ac,
                                               const float* __restrict__ Bc,
                                               float* __restrict__ Hin) {
  int chain = blockIdx.x * 256 + threadIdx.x;  // 8192 = b*E + e
  float H = lh0[chain];
  for (int c = 0; c < NCHUNK; ++c) {
    Hin[(size_t)c * NCHAIN + chain] = H;
    float a = Ac[(size_t)c * NCHAIN + chain] + H;
    float bv = Bc[(size_t)c * NCHAIN + chain];
    float m = fmaxf(a, bv);
    float d = fminf(a, bv) - m;
    H = m + __logf(1.f + __expf(d));
  }
}

// K4: replay scan (recomputing lv/lc from bf16 proj) with true incoming state;
// emit h_t (bf16) and out2 slices (f32)
__global__ __launch_bounds__(256) void k_scan3(const unsigned short* __restrict__ proj,
                                               const float* __restrict__ bfv,
                                               const float* __restrict__ Hin,
                                               unsigned short* __restrict__ ht,
                                               float* __restrict__ out2) {
  int idx = blockIdx.x * 256 + threadIdx.x;
  int e = idx & (SE - 1), b = (idx >> 11) & 3, c = idx >> 13;
  const float bk = bfv[e], bh = bfv[SE + e];
  float S = Hin[(size_t)c * NCHAIN + b * SE + e];
  size_t base = ((size_t)(b * ST + c * CHUNK) * (2 * SE)) + e;
  int t = c * CHUNK;
  size_t hto = ((size_t)(b * ST + t) * SE) + e;
  for (int i = 0; i < CHUNK; ++i, ++t) {
    float lc, lv;
    transform(bf2f(proj[base]) + bk, bf2f(proj[base + SE]) + bh, lc, lv);
    S = lse_step(lc, lv, S);
    ht[hto] = f2bf(__expf(S));
    if (t >= 2 && ((t - 2) % 3) == 0) {   // t in {2,5,...,4094}
      int j = (t - 2) / 3;
      out2[((size_t)b * 1365 + j) * SE + e] = S;
    }
    base += 2 * SE;
    hto += SE;
  }
}

// ---------- launch ----------
extern "C" void kernel_launch(void* const* d_in, const int* in_sizes, int n_in,
                              void* d_out, int out_size, void* d_ws, size_t ws_size,
                              hipStream_t stream) {
  const float* x   = (const float*)d_in[0];
  const float* lh0 = (const float*)d_in[1];
  const float* wf  = (const float*)d_in[2];
  const float* bfv = (const float*)d_in[3];
  const float* wd  = (const float*)d_in[4];
  float* out1 = (float*)d_out;
  float* out2 = out1 + (size_t)SB * ST * 1024;

  char* p = (char*)d_ws;
  unsigned short* proj = (unsigned short*)p; p += 16384ull * 4096 * 2;  // 134 MB bf16
  unsigned short* xhi  = (unsigned short*)p; p += 16384ull * 1024 * 2;
  unsigned short* wfh  = (unsigned short*)p; p += 4096ull * 1024 * 2;
  unsigned short* wdt  = (unsigned short*)p; p += 1024ull * 2048 * 2;
  unsigned short* ht   = (unsigned short*)p; p += 16384ull * 2048 * 2;  // 67 MB
  float* Ac            = (float*)p;          p += 64ull * 8192 * 4;
  float* Bc            = (float*)p;          p += 64ull * 8192 * 4;
  float* Hin           = (float*)p;          p += 64ull * 8192 * 4;

  // pre-passes
  hipLaunchKernelGGL(k_cast, dim3(16384), dim3(256), 0, stream, x, xhi);
  hipLaunchKernelGGL(k_transpose, dim3(128, 32), dim3(256), 0, stream, wf, wfh, 1024, 4096);
  hipLaunchKernelGGL(k_transpose, dim3(32, 64),  dim3(256), 0, stream, wd, wdt, 2048, 1024);
  // GEMM1 (bf16 in/out): proj = x @ w_f
  hipLaunchKernelGGL((k_gemm<true>), dim3(64, 16), dim3(512), 0, stream,
                     xhi, wfh, (void*)proj, 16384, 4096, 1024);
  // 3-pass chunked log-space scan (proj bf16, read-only; scan3 recomputes)
  hipLaunchKernelGGL(k_scan1, dim3(2048), dim3(256), 0, stream, proj, bfv, Ac, Bc);
  hipLaunchKernelGGL(k_scan2, dim3(32), dim3(256), 0, stream, lh0, Ac, Bc, Hin);
  hipLaunchKernelGGL(k_scan3, dim3(2048), dim3(256), 0, stream, proj, bfv, Hin, ht, out2);
  // GEMM2 (bf16 in, f32 out): out1 = h_t @ w_down
  hipLaunchKernelGGL((k_gemm<false>), dim3(64, 4), dim3(512), 0, stream,
                     ht, wdt, (void*)out1, 16384, 1024, 2048);
}